// Round 21
// baseline (109.055 us; speedup 1.0000x reference)
//
#include <hip/hip_runtime.h>
#include <hip/hip_bf16.h>

typedef unsigned short u16;
typedef unsigned int   u32;
typedef unsigned char  u8;

using bf16x8 = __attribute__((ext_vector_type(8))) short;  // 8 bf16 in 4 VGPRs
using f32x4  = __attribute__((ext_vector_type(4))) float;  // MFMA accumulator

#define NB 32
#define NP 1024
#define ND 256

__device__ __forceinline__ u16 f2bf(float x){
  u32 u = __float_as_uint(x);
  u += 0x7FFFu + ((u >> 16) & 1u);   // round-to-nearest-even
  return (u16)(u >> 16);
}

__device__ __forceinline__ float bf2f(u16 x){
  return __uint_as_float((u32)x << 16);
}

// ---- fp8 e4m3fn pack (builtin word-select must be a LITERAL -> template) ----
__device__ __forceinline__ u8 f2e4m3(float x){
  u32 b = __float_as_uint(x);
  u32 s = (b >> 31) << 7;
  float ax = __uint_as_float(b & 0x7fffffffu);
  if (!(ax < 464.f)) return (u8)(s | 0x7E);            // sat (fn: no inf), NaN->max
  if (ax < 0.001953125f) return (u8)s;                 // < 2^-9 -> 0
  if (ax < 0.015625f){                                 // denormal: m = round(x*512)
    u32 m = (u32)__float2int_rn(ax * 512.f);
    return (u8)(s | m);
  }
  u32 bb = b & 0x7fffffffu;
  bb += 0x7ffffu + ((bb >> 20) & 1u);                  // RNE to 3-bit mantissa
  int e = (int)(bb >> 23) - 127 + 7;
  u32 m = (bb >> 20) & 7u;
  if (e > 15 || (e == 15 && m == 7)) return (u8)(s | 0x7E);
  return (u8)(s | ((u32)e << 3) | m);
}
#if __has_builtin(__builtin_amdgcn_cvt_pk_fp8_f32)
template<bool HI>
__device__ __forceinline__ u32 pk_fp8(float a, float b, u32 old){
  return (u32)__builtin_amdgcn_cvt_pk_fp8_f32(a, b, (int)old, HI);
}
__device__ __forceinline__ u8 f8byte(float x){
  return (u8)(pk_fp8<false>(x, 0.f, 0) & 0xFFu);
}
#else
template<bool HI>
__device__ __forceinline__ u32 pk_fp8(float a, float b, u32 old){
  u32 v = (u32)f2e4m3(a) | ((u32)f2e4m3(b) << 8);
  return HI ? ((old & 0xFFFFu) | (v << 16)) : ((old & 0xFFFF0000u) | v);
}
__device__ __forceinline__ u8 f8byte(float x){ return f2e4m3(x); }
#endif

__device__ __forceinline__ void glds16(const void* g, void* l){
  __builtin_amdgcn_global_load_lds((const __attribute__((address_space(1))) void*)g,
                                   (__attribute__((address_space(3))) void*)l, 16, 0, 0);
}

// ---- fused prep: Pbf/PbfT/P8/sbv (Pbf restored for the bf16 MLP P-half) --------
__global__ void prep_pt(const float* __restrict__ P, const float* __restrict__ wi,
                        u16* __restrict__ Pbf, u16* __restrict__ PbfT,
                        u8* __restrict__ P8, float* __restrict__ sbv){
  const int b = blockIdx.y, jt = blockIdx.x;
  __shared__ __align__(16) u16 T[64][264];       // 33.8 KB (pad 264)
  const int tid = threadIdx.x;
  const int row = tid >> 2;                      // local j 0..63
  const int dq  = tid & 3;                       // d-quarter lane
  const size_t grow = (size_t)b * NP + jt * 64 + row;
  const float* prow = P + grow * ND;
  const float* wbp  = wi + ND;                   // wb = wi[256:512]
  float s = 0.f;
  #pragma unroll
  for (int it = 0; it < 4; ++it){
    const int d0 = it * 64 + dq * 16;            // per-lane 64B-contiguous chunks
    float4 a0 = *(const float4*)(prow + d0);
    float4 a1 = *(const float4*)(prow + d0 + 4);
    float4 a2 = *(const float4*)(prow + d0 + 8);
    float4 a3 = *(const float4*)(prow + d0 + 12);
    float4 w0 = *(const float4*)(wbp + d0);
    float4 w1 = *(const float4*)(wbp + d0 + 4);
    float4 w2 = *(const float4*)(wbp + d0 + 8);
    float4 w3 = *(const float4*)(wbp + d0 + 12);
    s += a0.x*w0.x + a0.y*w0.y + a0.z*w0.z + a0.w*w0.w;
    s += a1.x*w1.x + a1.y*w1.y + a1.z*w1.z + a1.w*w1.w;
    s += a2.x*w2.x + a2.y*w2.y + a2.z*w2.z + a2.w*w2.w;
    s += a3.x*w3.x + a3.y*w3.y + a3.z*w3.z + a3.w*w3.w;
    u16 tmp[16];
    tmp[0]=f2bf(a0.x); tmp[1]=f2bf(a0.y); tmp[2]=f2bf(a0.z); tmp[3]=f2bf(a0.w);
    tmp[4]=f2bf(a1.x); tmp[5]=f2bf(a1.y); tmp[6]=f2bf(a1.z); tmp[7]=f2bf(a1.w);
    tmp[8]=f2bf(a2.x); tmp[9]=f2bf(a2.y); tmp[10]=f2bf(a2.z); tmp[11]=f2bf(a2.w);
    tmp[12]=f2bf(a3.x); tmp[13]=f2bf(a3.y); tmp[14]=f2bf(a3.z); tmp[15]=f2bf(a3.w);
    *(uint4*)&T[row][d0]     = *(uint4*)tmp;
    *(uint4*)&T[row][d0 + 8] = *(uint4*)(tmp + 8);
    *(uint4*)(Pbf + grow * ND + d0)     = *(uint4*)tmp;
    *(uint4*)(Pbf + grow * ND + d0 + 8) = *(uint4*)(tmp + 8);
    // fp8 copy (16 values -> 16 bytes)
    u32 q0 = pk_fp8<false>(a0.x, a0.y, 0); q0 = pk_fp8<true>(a0.z, a0.w, q0);
    u32 q1 = pk_fp8<false>(a1.x, a1.y, 0); q1 = pk_fp8<true>(a1.z, a1.w, q1);
    u32 q2 = pk_fp8<false>(a2.x, a2.y, 0); q2 = pk_fp8<true>(a2.z, a2.w, q2);
    u32 q3 = pk_fp8<false>(a3.x, a3.y, 0); q3 = pk_fp8<true>(a3.z, a3.w, q3);
    uint4 pq; pq.x = q0; pq.y = q1; pq.z = q2; pq.w = q3;
    *(uint4*)(P8 + grow * ND + d0) = pq;
  }
  s += __shfl_xor(s, 1, 64);
  s += __shfl_xor(s, 2, 64);
  if (dq == 0) sbv[grow] = s;
  __syncthreads();
  #pragma unroll
  for (int it = 0; it < 8; ++it){
    int cc = tid + 256 * it;                     // 256 d-rows x 8 chunks
    int d = cc >> 3, c8 = cc & 7;
    u16 tmp[8];
    #pragma unroll
    for (int k = 0; k < 8; ++k) tmp[k] = T[c8 * 8 + k][d];
    *(uint4*)(PbfT + ((size_t)b * ND + d) * NP + jt * 64 + c8 * 8) = *(uint4*)tmp;
  }
}

// --- prep_w: K-split W pack. c<8 (P half) -> bf16 Wp[((t*8+c)*64+lane)*8+e];
//     c>=8 (attn half) -> fp8 x16 W8[((t*8+(c-8))*64+lane)*8+e] -----------------
__global__ void prep_w(const float* __restrict__ w1, const float* __restrict__ w2,
                       const float* __restrict__ w3,
                       u16* __restrict__ Wp, u8* __restrict__ W8){
  const int t = blockIdx.x;                       // 0..47
  const float* w = (t < 16) ? w1 : ((t < 32) ? w2 : w3);
  const int tid = threadIdx.x;
  #pragma unroll
  for (int j = 0; j < 4; ++j){
    int item = tid + 256 * j;                     // c*64 + lane (c uniform per wave)
    int c = item >> 6, lane = item & 63;
    int ncol = ((t & 15) << 4) + (lane & 15);
    int k0 = 32 * c + 8 * (lane >> 4);
    if (c < 8){
      u16 tmp[8];
      #pragma unroll
      for (int e = 0; e < 8; ++e) tmp[e] = f2bf(w[(size_t)(k0 + e) * 256 + ncol]);
      *(uint4*)(Wp + ((size_t)(t * 8 + c) * 64 + lane) * 8) = *(uint4*)tmp;
    } else {
      u32 lo32 = pk_fp8<false>(16.f * w[(size_t)(k0+0)*256+ncol], 16.f * w[(size_t)(k0+1)*256+ncol], 0);
      lo32     = pk_fp8<true >(16.f * w[(size_t)(k0+2)*256+ncol], 16.f * w[(size_t)(k0+3)*256+ncol], lo32);
      u32 hi32 = pk_fp8<false>(16.f * w[(size_t)(k0+4)*256+ncol], 16.f * w[(size_t)(k0+5)*256+ncol], 0);
      hi32     = pk_fp8<true >(16.f * w[(size_t)(k0+6)*256+ncol], 16.f * w[(size_t)(k0+7)*256+ncol], hi32);
      uint2 pv; pv.x = lo32; pv.y = hi32;
      *(uint2*)(W8 + ((size_t)(t * 8 + (c - 8)) * 64 + lane) * 8) = pv;
    }
  }
}

// ---------------- attention: r19 structure, fp8 epilogue output ------------------
__launch_bounds__(256, 2)
__global__ void attn_kernel(const float* __restrict__ P, const float* __restrict__ wi,
                            const u8* __restrict__ P8, const u16* __restrict__ PbfT,
                            const float* __restrict__ sbv, u8* __restrict__ attnb8){
  const int p    = blockIdx.x;
  const int bid  = ((p & 7) << 6) | (p >> 3);     // 64 consecutive bids per XCD
  const int b    = bid >> 4;
  const int q0   = (bid & 15) << 6;
  const int tid  = threadIdx.x;
  const int wave = tid >> 6, lane = tid & 63, lo = lane & 15, hi = lane >> 4;

  __shared__ __align__(16) u8  Kt8[64 * 256];     // 16 KB (fp8)
  __shared__ __align__(16) u16 VtA[256 * 64];     // 32 KB
  __shared__ __align__(16) u16 Sp[4][16][72];     // 9.2 KB
  __shared__ float sls[4][16];                    // per-q rescale factors
  __shared__ float lfin[64];                      // final softmax sums
  __shared__ u32 fastf[4];                        // per-wave fast-path flags
  char* KtB = (char*)Kt8;
  char* VtB = (char*)VtA;

  // ---- Q fragments (A-operand, fp8): q = 16 * P * wc ----
  long qf8[8];
  {
    const int qrow = q0 + wave * 16 + lo;
    const float* prow = P  + ((size_t)b * NP + qrow) * ND;
    const float* wcp  = wi + 512;
    #pragma unroll
    for (int c = 0; c < 8; ++c){
      const int d0 = 32 * c + 8 * hi;
      float4 a  = *(const float4*)(prow + d0);
      float4 a2 = *(const float4*)(prow + d0 + 4);
      float4 wa  = *(const float4*)(wcp + d0);
      float4 wa2 = *(const float4*)(wcp + d0 + 4);
      u32 w0 = pk_fp8<false>(16.f*a.x*wa.x,  16.f*a.y*wa.y,  0);
      w0     = pk_fp8<true >(16.f*a.z*wa.z,  16.f*a.w*wa.w,  w0);
      u32 w1 = pk_fp8<false>(16.f*a2.x*wa2.x, 16.f*a2.y*wa2.y, 0);
      w1     = pk_fp8<true >(16.f*a2.z*wa2.z, 16.f*a2.w*wa2.w, w1);
      qf8[c] = (long)(((unsigned long long)w1 << 32) | w0);
    }
  }

  f32x4 of[4][4];
  #pragma unroll
  for (int qt = 0; qt < 4; ++qt)
    #pragma unroll
    for (int dt = 0; dt < 4; ++dt) of[qt][dt] = (f32x4){0.f,0.f,0.f,0.f};
  float mx[4] = {-1e30f,-1e30f,-1e30f,-1e30f};
  float ls[4] = {0.f,0.f,0.f,0.f};

  const u8*  kslab = P8   + (size_t)b * NP * ND;   // fp8 row-major [j][d]
  const u16* vslab = PbfT + (size_t)b * ND * NP;   // bf16 d-major [d][j]

  auto stageK = [&](int kt){
    const int kbase = kt * 64;
    #pragma unroll
    for (int it = 0; it < 4; ++it){
      int off = it * 4096 + tid * 16;             // linear LDS dest byte
      int j   = off >> 8;                          // 256B fp8 rows
      int u   = ((off >> 4) & 15) ^ (j & 7);       // source 16B unit
      glds16((const char*)(kslab + (size_t)(kbase + j) * ND + u * 16), KtB + off);
    }
  };
  auto stageV = [&](int kt){
    const int kbase = kt * 64;
    #pragma unroll
    for (int it = 0; it < 8; ++it){
      int off = it * 4096 + tid * 16;
      int d   = off >> 7;
      int kc  = ((off >> 4) & 7) ^ (d & 7);
      glds16((const char*)(vslab + (size_t)d * NP + kbase + kc * 8), VtB + off);
    }
  };

  float sbc[4], sbn[4];
  stageK(0);
  stageV(0);
  #pragma unroll
  for (int nt = 0; nt < 4; ++nt) sbc[nt] = sbv[(size_t)b * NP + nt * 16 + lo];
  __syncthreads();                                 // drain: K0,V0 valid

  for (int kt = 0; kt < 16; ++kt){
    // ---- S = (16Q) K^T / 16 (fp8 MFMA; reads Kt8) ----
    f32x4 s[4];
    #pragma unroll
    for (int nt = 0; nt < 4; ++nt){
      f32x4 acc = (f32x4){0.f,0.f,0.f,0.f};
      #pragma unroll
      for (int c = 0; c < 8; ++c){
        int j  = nt * 16 + lo;
        int ad = j * 256 + (((2 * c + (hi >> 1)) ^ (j & 7)) << 4) + 8 * (hi & 1);
        long kf8 = *(const long*)(KtB + ad);
        acc = __builtin_amdgcn_mfma_f32_16x16x32_fp8_fp8(qf8[c], kf8, acc, 0, 0, 0);
      }
      float sv = sbc[nt];
      #pragma unroll
      for (int r = 0; r < 4; ++r) s[nt][r] = fmaf(acc[r], 0.0625f, sv);
    }

    // ---- deferred online softmax (owning wave: its 16 q rows) ----
    float scale[4] = {1.f, 1.f, 1.f, 1.f};
    int fast = 1;
    {
      float md = -1e30f;
      #pragma unroll
      for (int nt = 0; nt < 4; ++nt)
        #pragma unroll
        for (int r = 0; r < 4; ++r) md = fmaxf(md, s[nt][r] - mx[r]);
      if (!__all(md <= 8.f)){
        fast = 0;
        #pragma unroll
        for (int r = 0; r < 4; ++r){
          float v = fmaxf(fmaxf(s[0][r], s[1][r]), fmaxf(s[2][r], s[3][r]));
          v = fmaxf(v, __shfl_xor(v, 1, 64));
          v = fmaxf(v, __shfl_xor(v, 2, 64));
          v = fmaxf(v, __shfl_xor(v, 4, 64));
          v = fmaxf(v, __shfl_xor(v, 8, 64));
          float mnew = fmaxf(mx[r], v);
          scale[r] = __expf(mx[r] - mnew);
          mx[r] = mnew;
          ls[r] *= scale[r];
        }
      }
    }
    // exp + per-lane partial sums + repack P to Sp (bounded by e^8)
    #pragma unroll
    for (int nt = 0; nt < 4; ++nt)
      #pragma unroll
      for (int r = 0; r < 4; ++r){
        float pv = __expf(s[nt][r] - mx[r]);
        ls[r] += pv;
        Sp[wave][4 * hi + r][16 * nt + lo] = f2bf(pv);
      }
    if (lane == 0) fastf[wave] = (u32)fast;
    if (lo == 0){
      #pragma unroll
      for (int r = 0; r < 4; ++r) sls[wave][4 * hi + r] = scale[r];
    }

    __syncthreads();                  // barrier1: Kt reads done; Sp/sls/flags visible
    if (kt < 15) stageK(kt + 1);      // in flight across rescale+PV; drains at b2

    // ---- cross-wave rescale of O (skipped when all 4 waves were fast) ----
    if (!(fastf[0] & fastf[1] & fastf[2] & fastf[3])){
      #pragma unroll
      for (int qt = 0; qt < 4; ++qt){
        #pragma unroll
        for (int r = 0; r < 4; ++r){
          float sc = sls[qt][4 * hi + r];          // same-addr per 16 lanes: broadcast
          #pragma unroll
          for (int dt = 0; dt < 4; ++dt) of[qt][dt][r] *= sc;
        }
      }
    }

    // ---- O += P V, d-split: this wave owns d in [wave*64, wave*64+64) ----
    #pragma unroll
    for (int kk = 0; kk < 2; ++kk){
      bf16x8 pa[4];
      #pragma unroll
      for (int qt = 0; qt < 4; ++qt)
        pa[qt] = *(const bf16x8*)&Sp[qt][lo][32 * kk + 8 * hi];
      #pragma unroll
      for (int dt = 0; dt < 4; ++dt){
        int d  = wave * 64 + dt * 16 + lo;
        int ad = d * 128 + (((4 * kk + hi) ^ (d & 7)) << 4);
        bf16x8 vb = *(const bf16x8*)(VtB + ad);
        #pragma unroll
        for (int qt = 0; qt < 4; ++qt)
          of[qt][dt] = __builtin_amdgcn_mfma_f32_16x16x32_bf16(pa[qt], vb, of[qt][dt], 0, 0, 0);
      }
    }

    __syncthreads();                  // barrier2: Vt+Sp reads done; drains K(t+1)
    if (kt < 15){
      stageV(kt + 1);                 // in flight across next QK^T+softmax; drains at b1
      #pragma unroll
      for (int nt = 0; nt < 4; ++nt)
        sbn[nt] = sbv[(size_t)b * NP + (kt + 1) * 64 + nt * 16 + lo];
      sbc[0] = sbn[0]; sbc[1] = sbn[1]; sbc[2] = sbn[2]; sbc[3] = sbn[3];
    }
  }

  // ---- epilogue: publish per-q l, then O /= l, store fp8 ----
  #pragma unroll
  for (int r = 0; r < 4; ++r){
    ls[r] += __shfl_xor(ls[r], 1, 64);
    ls[r] += __shfl_xor(ls[r], 2, 64);
    ls[r] += __shfl_xor(ls[r], 4, 64);
    ls[r] += __shfl_xor(ls[r], 8, 64);
  }
  if (lo == 0){
    #pragma unroll
    for (int r = 0; r < 4; ++r) lfin[wave * 16 + 4 * hi + r] = ls[r];
  }
  __syncthreads();
  #pragma unroll
  for (int qt = 0; qt < 4; ++qt){
    #pragma unroll
    for (int r = 0; r < 4; ++r){
      const float inv = 1.f / lfin[qt * 16 + 4 * hi + r];   // broadcast read
      const int qrow = q0 + qt * 16 + 4 * hi + r;
      #pragma unroll
      for (int dt = 0; dt < 4; ++dt){
        float o = of[qt][dt][r] * inv;
        attnb8[((size_t)b * NP + qrow) * ND + wave * 64 + dt * 16 + lo] = f8byte(o);
      }
    }
  }
}

// ---------------- MLP: K-split mixed precision, fused gate epilogue --------------
// Phase A (attn half, K 256..511): fp8 A (attnb8) x fp8 W(x16) -> acc; then
// acc *= 0.0625; Phase B (P half, K 0..255): bf16 A (Pbf) x bf16 W accumulates
// on top (K-order commutes). r20's failure decomposed: P-half fp8 + W-vs-P fp8
// were the dominant error terms -> keep those bf16; attn-half terms are ~10x
// smaller. fp8 layouts identical to the r19/r20-verified ones.
__launch_bounds__(256, 2)
__global__ void mlp_kernel(const u16* __restrict__ Pbf, const u8* __restrict__ attnb8,
                           const u16* __restrict__ Wp, const u8* __restrict__ W8,
                           const float* __restrict__ Pf,
                           const float* __restrict__ b1, const float* __restrict__ b2,
                           const float* __restrict__ b3, float* __restrict__ out){
  const int p    = blockIdx.x;
  const int swz  = ((p & 7) << 7) | (p >> 3);     // XCD-chunked
  const int mt   = swz >> 2, cg = swz & 3;
  const int tid  = threadIdx.x;
  const int wave = tid >> 6, lane = tid & 63, lo = lane & 15, hi = lane >> 4;
  const int tq   = 4 * cg + wave;
  const int m0   = mt * 128;

  __shared__ __align__(16) u16 Ab16[2][128 * 64]; // 2 x 16 KB (bf16, r19 swizzle)
  __shared__ __align__(16) u8  Ab8[2][128 * 64];  // 2 x 8 KB (fp8, r20 swizzle)

  f32x4 acc[3][8];
  #pragma unroll
  for (int e = 0; e < 3; ++e)
    #pragma unroll
    for (int m = 0; m < 8; ++m) acc[e][m] = (f32x4){0.f,0.f,0.f,0.f};

  auto stage16 = [&](int s, int buf){             // Pbf K-slice s (0..3)
    const u16* xs = Pbf + (size_t)m0 * ND + s * 64;
    char* dst = (char*)Ab16[buf];
    #pragma unroll
    for (int it = 0; it < 4; ++it){
      int off = it * 4096 + tid * 16;
      int row = off >> 7;                          // 128B per row
      int cl  = (off & 127) ^ ((row & 7) << 4);
      glds16((const char*)(xs + (size_t)row * ND) + cl, dst + off);
    }
  };
  auto stage8 = [&](int s, int buf){              // attnb8 K-slice s (0..3)
    const u8* xs = attnb8 + (size_t)m0 * ND + s * 64;
    char* dst = (char*)Ab8[buf];
    #pragma unroll
    for (int it = 0; it < 2; ++it){
      int off = it * 4096 + tid * 16;
      int row = off >> 6;                          // 64B per row
      int u   = ((off >> 4) & 3) ^ ((row >> 1) & 3);
      glds16((const char*)(xs + (size_t)row * ND + u * 16), dst + off);
    }
  };

  // ---- Phase A: attn half, fp8 ----
  stage8(0, 0);
  __syncthreads();
  for (int s = 0; s < 4; ++s){
    if (s < 3) stage8(s + 1, (s + 1) & 1);
    else       stage16(0, 0);                      // prefetch phase B's first tile
    const char* ab = (const char*)Ab8[s & 1];
    #pragma unroll
    for (int cc = 0; cc < 2; ++cc){
      const int c = 2 * s + cc;                    // 0..7 -> W8 index
      long wf8[3];
      #pragma unroll
      for (int e = 0; e < 3; ++e)
        wf8[e] = *(const long*)(W8 + ((size_t)((tq + 16 * e) * 8 + c) * 64 + lane) * 8);
      #pragma unroll
      for (int m = 0; m < 8; ++m){
        int row = 16 * m + lo;
        int ad  = row * 64 + (((2 * cc + (hi >> 1)) ^ ((row >> 1) & 3)) << 4) + 8 * (hi & 1);
        long af8 = *(const long*)(ab + ad);
        #pragma unroll
        for (int e = 0; e < 3; ++e)
          acc[e][m] = __builtin_amdgcn_mfma_f32_16x16x32_fp8_fp8(af8, wf8[e], acc[e][m], 0, 0, 0);
      }
    }
    __syncthreads();
  }

  // ---- fold x16 W scale out of the fp8 partial sums ----
  #pragma unroll
  for (int e = 0; e < 3; ++e)
    #pragma unroll
    for (int m = 0; m < 8; ++m)
      #pragma unroll
      for (int r = 0; r < 4; ++r) acc[e][m][r] *= 0.0625f;

  // ---- Phase B: P half, bf16 ----
  for (int s = 0; s < 4; ++s){
    if (s < 3) stage16(s + 1, (s + 1) & 1);
    const char* ab = (const char*)Ab16[s & 1];
    #pragma unroll
    for (int cc = 0; cc < 2; ++cc){
      const int c = 2 * s + cc;                    // 0..7 -> Wp index
      bf16x8 wf[3];
      #pragma unroll
      for (int e = 0; e < 3; ++e)
        wf[e] = *(const bf16x8*)(Wp + ((size_t)((tq + 16 * e) * 8 + c) * 64 + lane) * 8);
      #pragma unroll
      for (int m = 0; m < 8; ++m){
        int row = 16 * m + lo;
        bf16x8 af = *(const bf16x8*)(ab + row * 128 + ((64 * cc + 16 * hi) ^ ((row & 7) << 4)));
        #pragma unroll
        for (int e = 0; e < 3; ++e)
          acc[e][m] = __builtin_amdgcn_mfma_f32_16x16x32_bf16(af, wf[e], acc[e][m], 0, 0, 0);
      }
    }
    __syncthreads();
  }

  // ---- fused gate epilogue (pv from fp32 P) ----
  const int d = 16 * tq + lo;
  const float bb1 = b1[d], bb2 = b2[d], bb3 = b3[d];
  #pragma unroll
  for (int m = 0; m < 8; ++m){
    #pragma unroll
    for (int r = 0; r < 4; ++r){
      const int row = m0 + 16 * m + 4 * hi + r;
      float y1 = acc[0][m][r] + bb1;
      float y2 = acc[1][m][r] + bb2;
      float y3 = acc[2][m][r] + bb3;
      float pv = Pf[(size_t)row * ND + d];
      float e2 = __expf(2.f * y1);
      float z  = (e2 - 1.f) / (e2 + 1.f);          // tanh
      float rr = 1.f / (1.f + __expf(-y2));        // sigmoid
      float ff = 1.f / (1.f + __expf(-y3));        // sigmoid
      out[(size_t)row * ND + d] = rr * pv + ff * z;
    }
  }
}

extern "C" void kernel_launch(void* const* d_in, const int* in_sizes, int n_in,
                              void* d_out, int out_size, void* d_ws, size_t ws_size,
                              hipStream_t stream){
  const float* P  = (const float*)d_in[0];
  const float* wi = (const float*)d_in[1];
  const float* w1 = (const float*)d_in[2];
  const float* w2 = (const float*)d_in[3];
  const float* w3 = (const float*)d_in[4];
  const float* b1 = (const float*)d_in[5];
  const float* b2 = (const float*)d_in[6];
  const float* b3 = (const float*)d_in[7];
  float* out = (float*)d_out;

  char* ws = (char*)d_ws;
  u16*   PbfT  = (u16*)  (ws);                        // 16 MB
  u8*    P8    = (u8*)   (ws + (16u << 20));          // 8 MB
  u8*    atn8  = (u8*)   (ws + (24u << 20));          // 8 MB (fp8 attn out)
  u16*   Pbf   = (u16*)  (ws + (32u << 20));          // 16 MB (bf16 MLP P-half)
  u16*   Wp    = (u16*)  (ws + (48u << 20));          // 384 KB bf16 W (c<8)
  u8*    W8    = (u8*)   (ws + (48u << 20) + 524288); // 192 KB fp8 W (c>=8)
  float* sbv   = (float*)(ws + (49u << 20));          // 128 KB

  prep_pt<<<dim3(16, 32), 256, 0, stream>>>(P, wi, Pbf, PbfT, P8, sbv);
  prep_w<<<48, 256, 0, stream>>>(w1, w2, w3, Wp, W8);
  attn_kernel<<<512, 256, 0, stream>>>(P, wi, P8, PbfT, sbv, atn8);
  mlp_kernel<<<1024, 256, 0, stream>>>(Pbf, atn8, Wp, W8, P, b1, b2, b3, out);
}

// Round 22
// 106.814 us; speedup vs baseline: 1.0210x; 1.0210x over previous
//
#include <hip/hip_runtime.h>
#include <hip/hip_bf16.h>

typedef unsigned short u16;
typedef unsigned int   u32;
typedef unsigned char  u8;

using bf16x8 = __attribute__((ext_vector_type(8))) short;  // 8 bf16 in 4 VGPRs
using f32x4  = __attribute__((ext_vector_type(4))) float;  // MFMA accumulator

#define NB 32
#define NP 1024
#define ND 256

__device__ __forceinline__ u16 f2bf(float x){
  u32 u = __float_as_uint(x);
  u += 0x7FFFu + ((u >> 16) & 1u);   // round-to-nearest-even
  return (u16)(u >> 16);
}

__device__ __forceinline__ float bf2f(u16 x){
  return __uint_as_float((u32)x << 16);
}

// ---- fp8 e4m3fn pack (builtin word-select must be a LITERAL -> template) ----
__device__ __forceinline__ u8 f2e4m3(float x){
  u32 b = __float_as_uint(x);
  u32 s = (b >> 31) << 7;
  float ax = __uint_as_float(b & 0x7fffffffu);
  if (!(ax < 464.f)) return (u8)(s | 0x7E);            // sat (fn: no inf), NaN->max
  if (ax < 0.001953125f) return (u8)s;                 // < 2^-9 -> 0
  if (ax < 0.015625f){                                 // denormal: m = round(x*512)
    u32 m = (u32)__float2int_rn(ax * 512.f);
    return (u8)(s | m);
  }
  u32 bb = b & 0x7fffffffu;
  bb += 0x7ffffu + ((bb >> 20) & 1u);                  // RNE to 3-bit mantissa
  int e = (int)(bb >> 23) - 127 + 7;
  u32 m = (bb >> 20) & 7u;
  if (e > 15 || (e == 15 && m == 7)) return (u8)(s | 0x7E);
  return (u8)(s | ((u32)e << 3) | m);
}
#if __has_builtin(__builtin_amdgcn_cvt_pk_fp8_f32)
template<bool HI>
__device__ __forceinline__ u32 pk_fp8(float a, float b, u32 old){
  return (u32)__builtin_amdgcn_cvt_pk_fp8_f32(a, b, (int)old, HI);
}
__device__ __forceinline__ u8 f8byte(float x){
  return (u8)(pk_fp8<false>(x, 0.f, 0) & 0xFFu);
}
#else
template<bool HI>
__device__ __forceinline__ u32 pk_fp8(float a, float b, u32 old){
  u32 v = (u32)f2e4m3(a) | ((u32)f2e4m3(b) << 8);
  return HI ? ((old & 0xFFFFu) | (v << 16)) : ((old & 0xFFFF0000u) | v);
}
__device__ __forceinline__ u8 f8byte(float x){ return f2e4m3(x); }
#endif

__device__ __forceinline__ void glds16(const void* g, void* l){
  __builtin_amdgcn_global_load_lds((const __attribute__((address_space(1))) void*)g,
                                   (__attribute__((address_space(3))) void*)l, 16, 0, 0);
}

// ---- fused prep: Pbf (bf16), PT8 (fp8 transpose, replaces PbfT), P8, sbv -------
__global__ void prep_pt(const float* __restrict__ P, const float* __restrict__ wi,
                        u16* __restrict__ Pbf, u8* __restrict__ PT8,
                        u8* __restrict__ P8, float* __restrict__ sbv){
  const int b = blockIdx.y, jt = blockIdx.x;
  __shared__ __align__(16) u16 T[64][264];       // 33.8 KB (pad 264)
  const int tid = threadIdx.x;
  const int row = tid >> 2;                      // local j 0..63
  const int dq  = tid & 3;                       // d-quarter lane
  const size_t grow = (size_t)b * NP + jt * 64 + row;
  const float* prow = P + grow * ND;
  const float* wbp  = wi + ND;                   // wb = wi[256:512]
  float s = 0.f;
  #pragma unroll
  for (int it = 0; it < 4; ++it){
    const int d0 = it * 64 + dq * 16;            // per-lane 64B-contiguous chunks
    float4 a0 = *(const float4*)(prow + d0);
    float4 a1 = *(const float4*)(prow + d0 + 4);
    float4 a2 = *(const float4*)(prow + d0 + 8);
    float4 a3 = *(const float4*)(prow + d0 + 12);
    float4 w0 = *(const float4*)(wbp + d0);
    float4 w1 = *(const float4*)(wbp + d0 + 4);
    float4 w2 = *(const float4*)(wbp + d0 + 8);
    float4 w3 = *(const float4*)(wbp + d0 + 12);
    s += a0.x*w0.x + a0.y*w0.y + a0.z*w0.z + a0.w*w0.w;
    s += a1.x*w1.x + a1.y*w1.y + a1.z*w1.z + a1.w*w1.w;
    s += a2.x*w2.x + a2.y*w2.y + a2.z*w2.z + a2.w*w2.w;
    s += a3.x*w3.x + a3.y*w3.y + a3.z*w3.z + a3.w*w3.w;
    u16 tmp[16];
    tmp[0]=f2bf(a0.x); tmp[1]=f2bf(a0.y); tmp[2]=f2bf(a0.z); tmp[3]=f2bf(a0.w);
    tmp[4]=f2bf(a1.x); tmp[5]=f2bf(a1.y); tmp[6]=f2bf(a1.z); tmp[7]=f2bf(a1.w);
    tmp[8]=f2bf(a2.x); tmp[9]=f2bf(a2.y); tmp[10]=f2bf(a2.z); tmp[11]=f2bf(a2.w);
    tmp[12]=f2bf(a3.x); tmp[13]=f2bf(a3.y); tmp[14]=f2bf(a3.z); tmp[15]=f2bf(a3.w);
    *(uint4*)&T[row][d0]     = *(uint4*)tmp;
    *(uint4*)&T[row][d0 + 8] = *(uint4*)(tmp + 8);
    *(uint4*)(Pbf + grow * ND + d0)     = *(uint4*)tmp;
    *(uint4*)(Pbf + grow * ND + d0 + 8) = *(uint4*)(tmp + 8);
    // fp8 copy (16 values -> 16 bytes)
    u32 q0 = pk_fp8<false>(a0.x, a0.y, 0); q0 = pk_fp8<true>(a0.z, a0.w, q0);
    u32 q1 = pk_fp8<false>(a1.x, a1.y, 0); q1 = pk_fp8<true>(a1.z, a1.w, q1);
    u32 q2 = pk_fp8<false>(a2.x, a2.y, 0); q2 = pk_fp8<true>(a2.z, a2.w, q2);
    u32 q3 = pk_fp8<false>(a3.x, a3.y, 0); q3 = pk_fp8<true>(a3.z, a3.w, q3);
    uint4 pq; pq.x = q0; pq.y = q1; pq.z = q2; pq.w = q3;
    *(uint4*)(P8 + grow * ND + d0) = pq;
  }
  s += __shfl_xor(s, 1, 64);
  s += __shfl_xor(s, 2, 64);
  if (dq == 0) sbv[grow] = s;
  __syncthreads();
  // fp8 transpose out: PT8[b][d][j]
  #pragma unroll
  for (int it = 0; it < 8; ++it){
    int cc = tid + 256 * it;                     // 256 d-rows x 8 chunks
    int d = cc >> 3, c8 = cc & 7;
    float v0 = bf2f(T[c8 * 8 + 0][d]), v1 = bf2f(T[c8 * 8 + 1][d]);
    float v2 = bf2f(T[c8 * 8 + 2][d]), v3 = bf2f(T[c8 * 8 + 3][d]);
    float v4 = bf2f(T[c8 * 8 + 4][d]), v5 = bf2f(T[c8 * 8 + 5][d]);
    float v6 = bf2f(T[c8 * 8 + 6][d]), v7 = bf2f(T[c8 * 8 + 7][d]);
    u32 lo32 = pk_fp8<false>(v0, v1, 0); lo32 = pk_fp8<true>(v2, v3, lo32);
    u32 hi32 = pk_fp8<false>(v4, v5, 0); hi32 = pk_fp8<true>(v6, v7, hi32);
    uint2 pv; pv.x = lo32; pv.y = hi32;
    *(uint2*)(PT8 + ((size_t)b * ND + d) * NP + jt * 64 + c8 * 8) = pv;
  }
}

// --- prep_w: K-split W pack. c<8 (P half) -> bf16 Wp; c>=8 (attn half) -> fp8 x16
__global__ void prep_w(const float* __restrict__ w1, const float* __restrict__ w2,
                       const float* __restrict__ w3,
                       u16* __restrict__ Wp, u8* __restrict__ W8){
  const int t = blockIdx.x;                       // 0..47
  const float* w = (t < 16) ? w1 : ((t < 32) ? w2 : w3);
  const int tid = threadIdx.x;
  #pragma unroll
  for (int j = 0; j < 4; ++j){
    int item = tid + 256 * j;                     // c*64 + lane (c uniform per wave)
    int c = item >> 6, lane = item & 63;
    int ncol = ((t & 15) << 4) + (lane & 15);
    int k0 = 32 * c + 8 * (lane >> 4);
    if (c < 8){
      u16 tmp[8];
      #pragma unroll
      for (int e = 0; e < 8; ++e) tmp[e] = f2bf(w[(size_t)(k0 + e) * 256 + ncol]);
      *(uint4*)(Wp + ((size_t)(t * 8 + c) * 64 + lane) * 8) = *(uint4*)tmp;
    } else {
      u32 lo32 = pk_fp8<false>(16.f * w[(size_t)(k0+0)*256+ncol], 16.f * w[(size_t)(k0+1)*256+ncol], 0);
      lo32     = pk_fp8<true >(16.f * w[(size_t)(k0+2)*256+ncol], 16.f * w[(size_t)(k0+3)*256+ncol], lo32);
      u32 hi32 = pk_fp8<false>(16.f * w[(size_t)(k0+4)*256+ncol], 16.f * w[(size_t)(k0+5)*256+ncol], 0);
      hi32     = pk_fp8<true >(16.f * w[(size_t)(k0+6)*256+ncol], 16.f * w[(size_t)(k0+7)*256+ncol], hi32);
      uint2 pv; pv.x = lo32; pv.y = hi32;
      *(uint2*)(W8 + ((size_t)(t * 8 + (c - 8)) * 64 + lane) * 8) = pv;
    }
  }
}

// ---------------- attention: full-fp8 operand paths (QK^T and PV) ---------------
// fp8 PV: V from PT8 (fp8), P stored fp8 at scale 1/8 (p <= e^8 = 2981 -> 372,
// no sat; ls keeps exact fp32 p; final inv = 8/l). LDS reads/block-tile 80->48KB
// (r17 rule: bytes=time on this path). Bank derivations (bijection rule):
//   K8: as r19 (verified). V8: phys = d*64 + 8*(u ^ (d&6)), u = 8B j-chunk; swz
//   even so glds 16B granules stay contiguous; read quad 4(lo&1)+((4kk+hi)^(lo&6))>>1
//   enumerated bijective. Sp8 pitch 80: read quad (5lo+..)%8 bijective.
__launch_bounds__(256, 2)
__global__ void attn_kernel(const float* __restrict__ P, const float* __restrict__ wi,
                            const u8* __restrict__ P8, const u8* __restrict__ PT8,
                            const float* __restrict__ sbv, u8* __restrict__ attnb8){
  const int p    = blockIdx.x;
  const int bid  = ((p & 7) << 6) | (p >> 3);     // 64 consecutive bids per XCD
  const int b    = bid >> 4;
  const int q0   = (bid & 15) << 6;
  const int tid  = threadIdx.x;
  const int wave = tid >> 6, lane = tid & 63, lo = lane & 15, hi = lane >> 4;

  __shared__ __align__(16) u8  Kt8[64 * 256];     // 16 KB (fp8)
  __shared__ __align__(16) u8  Vt8[256 * 64];     // 16 KB (fp8)
  __shared__ __align__(16) u8  Sp8[4][16][80];    // 5 KB (fp8 P, pitch 80)
  __shared__ float sls[4][16];                    // per-q rescale factors
  __shared__ float lfin[64];                      // final softmax sums
  __shared__ u32 fastf[4];                        // per-wave fast-path flags
  char* KtB = (char*)Kt8;
  char* VtB = (char*)Vt8;

  // ---- Q fragments (A-operand, fp8): q = 16 * P * wc ----
  long qf8[8];
  {
    const int qrow = q0 + wave * 16 + lo;
    const float* prow = P  + ((size_t)b * NP + qrow) * ND;
    const float* wcp  = wi + 512;
    #pragma unroll
    for (int c = 0; c < 8; ++c){
      const int d0 = 32 * c + 8 * hi;
      float4 a  = *(const float4*)(prow + d0);
      float4 a2 = *(const float4*)(prow + d0 + 4);
      float4 wa  = *(const float4*)(wcp + d0);
      float4 wa2 = *(const float4*)(wcp + d0 + 4);
      u32 w0 = pk_fp8<false>(16.f*a.x*wa.x,  16.f*a.y*wa.y,  0);
      w0     = pk_fp8<true >(16.f*a.z*wa.z,  16.f*a.w*wa.w,  w0);
      u32 w1 = pk_fp8<false>(16.f*a2.x*wa2.x, 16.f*a2.y*wa2.y, 0);
      w1     = pk_fp8<true >(16.f*a2.z*wa2.z, 16.f*a2.w*wa2.w, w1);
      qf8[c] = (long)(((unsigned long long)w1 << 32) | w0);
    }
  }

  f32x4 of[4][4];
  #pragma unroll
  for (int qt = 0; qt < 4; ++qt)
    #pragma unroll
    for (int dt = 0; dt < 4; ++dt) of[qt][dt] = (f32x4){0.f,0.f,0.f,0.f};
  float mx[4] = {-1e30f,-1e30f,-1e30f,-1e30f};
  float ls[4] = {0.f,0.f,0.f,0.f};

  const u8* kslab = P8  + (size_t)b * NP * ND;   // fp8 row-major [j][d]
  const u8* vslab = PT8 + (size_t)b * ND * NP;   // fp8 d-major  [d][j]

  auto stageK = [&](int kt){
    const int kbase = kt * 64;
    #pragma unroll
    for (int it = 0; it < 4; ++it){
      int off = it * 4096 + tid * 16;             // linear LDS dest byte
      int j   = off >> 8;                          // 256B fp8 rows
      int u   = ((off >> 4) & 15) ^ (j & 7);       // source 16B unit
      glds16((const char*)(kslab + (size_t)(kbase + j) * ND + u * 16), KtB + off);
    }
  };
  auto stageV = [&](int kt){
    const int kbase = kt * 64;
    #pragma unroll
    for (int it = 0; it < 4; ++it){
      int off = it * 4096 + tid * 16;
      int d   = off >> 6;                          // 64B fp8 rows
      int t   = (off >> 4) & 3;                    // dest 16B unit
      int u   = t ^ ((d >> 1) & 3);                // source 16B unit (swz even)
      glds16((const char*)(vslab + (size_t)d * NP + kbase + u * 16), VtB + off);
    }
  };

  float sbc[4], sbn[4];
  stageK(0);
  stageV(0);
  #pragma unroll
  for (int nt = 0; nt < 4; ++nt) sbc[nt] = sbv[(size_t)b * NP + nt * 16 + lo];
  __syncthreads();                                 // drain: K0,V0 valid

  for (int kt = 0; kt < 16; ++kt){
    // ---- S = (16Q) K^T / 16 (fp8 MFMA; reads Kt8) ----
    f32x4 s[4];
    #pragma unroll
    for (int nt = 0; nt < 4; ++nt){
      f32x4 acc = (f32x4){0.f,0.f,0.f,0.f};
      #pragma unroll
      for (int c = 0; c < 8; ++c){
        int j  = nt * 16 + lo;
        int ad = j * 256 + (((2 * c + (hi >> 1)) ^ (j & 7)) << 4) + 8 * (hi & 1);
        long kf8 = *(const long*)(KtB + ad);
        acc = __builtin_amdgcn_mfma_f32_16x16x32_fp8_fp8(qf8[c], kf8, acc, 0, 0, 0);
      }
      float sv = sbc[nt];
      #pragma unroll
      for (int r = 0; r < 4; ++r) s[nt][r] = fmaf(acc[r], 0.0625f, sv);
    }

    // ---- deferred online softmax (owning wave: its 16 q rows) ----
    float scale[4] = {1.f, 1.f, 1.f, 1.f};
    int fast = 1;
    {
      float md = -1e30f;
      #pragma unroll
      for (int nt = 0; nt < 4; ++nt)
        #pragma unroll
        for (int r = 0; r < 4; ++r) md = fmaxf(md, s[nt][r] - mx[r]);
      if (!__all(md <= 8.f)){
        fast = 0;
        #pragma unroll
        for (int r = 0; r < 4; ++r){
          float v = fmaxf(fmaxf(s[0][r], s[1][r]), fmaxf(s[2][r], s[3][r]));
          v = fmaxf(v, __shfl_xor(v, 1, 64));
          v = fmaxf(v, __shfl_xor(v, 2, 64));
          v = fmaxf(v, __shfl_xor(v, 4, 64));
          v = fmaxf(v, __shfl_xor(v, 8, 64));
          float mnew = fmaxf(mx[r], v);
          scale[r] = __expf(mx[r] - mnew);
          mx[r] = mnew;
          ls[r] *= scale[r];
        }
      }
    }
    // exp + per-lane partial sums + pack P/8 to Sp8 (p/8 <= 372 < 448 sat)
    #pragma unroll
    for (int nt = 0; nt < 4; ++nt)
      #pragma unroll
      for (int r = 0; r < 4; ++r){
        float pv = __expf(s[nt][r] - mx[r]);
        ls[r] += pv;
        Sp8[wave][4 * hi + r][16 * nt + lo] = f8byte(pv * 0.125f);
      }
    if (lane == 0) fastf[wave] = (u32)fast;
    if (lo == 0){
      #pragma unroll
      for (int r = 0; r < 4; ++r) sls[wave][4 * hi + r] = scale[r];
    }

    __syncthreads();                  // barrier1: Kt reads done; Sp8/sls visible
    if (kt < 15) stageK(kt + 1);      // in flight across rescale+PV; drains at b2

    // ---- cross-wave rescale of O (skipped when all 4 waves were fast) ----
    if (!(fastf[0] & fastf[1] & fastf[2] & fastf[3])){
      #pragma unroll
      for (int qt = 0; qt < 4; ++qt){
        #pragma unroll
        for (int r = 0; r < 4; ++r){
          float sc = sls[qt][4 * hi + r];          // same-addr per 16 lanes: broadcast
          #pragma unroll
          for (int dt = 0; dt < 4; ++dt) of[qt][dt][r] *= sc;
        }
      }
    }

    // ---- O += (P/8) V, fp8 MFMA; this wave owns d in [wave*64, wave*64+64) ----
    #pragma unroll
    for (int kk = 0; kk < 2; ++kk){
      long pa8[4];
      #pragma unroll
      for (int qt = 0; qt < 4; ++qt)
        pa8[qt] = *(const long*)&Sp8[qt][lo][32 * kk + 8 * hi];
      #pragma unroll
      for (int dt = 0; dt < 4; ++dt){
        int d  = wave * 64 + dt * 16 + lo;
        int ad = d * 64 + (((4 * kk + hi) ^ (d & 6)) << 3);
        long vb8 = *(const long*)(VtB + ad);
        #pragma unroll
        for (int qt = 0; qt < 4; ++qt)
          of[qt][dt] = __builtin_amdgcn_mfma_f32_16x16x32_fp8_fp8(pa8[qt], vb8, of[qt][dt], 0, 0, 0);
      }
    }

    __syncthreads();                  // barrier2: Vt+Sp8 reads done; drains K(t+1)
    if (kt < 15){
      stageV(kt + 1);                 // in flight across next QK^T+softmax; drains at b1
      #pragma unroll
      for (int nt = 0; nt < 4; ++nt)
        sbn[nt] = sbv[(size_t)b * NP + (kt + 1) * 64 + nt * 16 + lo];
      sbc[0] = sbn[0]; sbc[1] = sbn[1]; sbc[2] = sbn[2]; sbc[3] = sbn[3];
    }
  }

  // ---- epilogue: publish per-q l, then O = 8*of/l, store fp8 ----
  #pragma unroll
  for (int r = 0; r < 4; ++r){
    ls[r] += __shfl_xor(ls[r], 1, 64);
    ls[r] += __shfl_xor(ls[r], 2, 64);
    ls[r] += __shfl_xor(ls[r], 4, 64);
    ls[r] += __shfl_xor(ls[r], 8, 64);
  }
  if (lo == 0){
    #pragma unroll
    for (int r = 0; r < 4; ++r) lfin[wave * 16 + 4 * hi + r] = ls[r];
  }
  __syncthreads();
  #pragma unroll
  for (int qt = 0; qt < 4; ++qt){
    #pragma unroll
    for (int r = 0; r < 4; ++r){
      const float inv = 8.f / lfin[qt * 16 + 4 * hi + r];   // folds the 1/8 P-scale
      const int qrow = q0 + qt * 16 + 4 * hi + r;
      #pragma unroll
      for (int dt = 0; dt < 4; ++dt){
        float o = of[qt][dt][r] * inv;
        attnb8[((size_t)b * NP + qrow) * ND + wave * 64 + dt * 16 + lo] = f8byte(o);
      }
    }
  }
}

// ---------------- MLP: K-split mixed precision (r21, pv from Pbf) ----------------
__launch_bounds__(256, 2)
__global__ void mlp_kernel(const u16* __restrict__ Pbf, const u8* __restrict__ attnb8,
                           const u16* __restrict__ Wp, const u8* __restrict__ W8,
                           const float* __restrict__ b1, const float* __restrict__ b2,
                           const float* __restrict__ b3, float* __restrict__ out){
  const int p    = blockIdx.x;
  const int swz  = ((p & 7) << 7) | (p >> 3);     // XCD-chunked
  const int mt   = swz >> 2, cg = swz & 3;
  const int tid  = threadIdx.x;
  const int wave = tid >> 6, lane = tid & 63, lo = lane & 15, hi = lane >> 4;
  const int tq   = 4 * cg + wave;
  const int m0   = mt * 128;

  __shared__ __align__(16) u16 Ab16[2][128 * 64]; // 2 x 16 KB (bf16)
  __shared__ __align__(16) u8  Ab8[2][128 * 64];  // 2 x 8 KB (fp8)

  f32x4 acc[3][8];
  #pragma unroll
  for (int e = 0; e < 3; ++e)
    #pragma unroll
    for (int m = 0; m < 8; ++m) acc[e][m] = (f32x4){0.f,0.f,0.f,0.f};

  auto stage16 = [&](int s, int buf){             // Pbf K-slice s (0..3)
    const u16* xs = Pbf + (size_t)m0 * ND + s * 64;
    char* dst = (char*)Ab16[buf];
    #pragma unroll
    for (int it = 0; it < 4; ++it){
      int off = it * 4096 + tid * 16;
      int row = off >> 7;                          // 128B per row
      int cl  = (off & 127) ^ ((row & 7) << 4);
      glds16((const char*)(xs + (size_t)row * ND) + cl, dst + off);
    }
  };
  auto stage8 = [&](int s, int buf){              // attnb8 K-slice s (0..3)
    const u8* xs = attnb8 + (size_t)m0 * ND + s * 64;
    char* dst = (char*)Ab8[buf];
    #pragma unroll
    for (int it = 0; it < 2; ++it){
      int off = it * 4096 + tid * 16;
      int row = off >> 6;                          // 64B per row
      int u   = ((off >> 4) & 3) ^ ((row >> 1) & 3);
      glds16((const char*)(xs + (size_t)row * ND + u * 16), dst + off);
    }
  };

  // ---- Phase A: attn half, fp8 ----
  stage8(0, 0);
  __syncthreads();
  for (int s = 0; s < 4; ++s){
    if (s < 3) stage8(s + 1, (s + 1) & 1);
    else       stage16(0, 0);                      // prefetch phase B's first tile
    const char* ab = (const char*)Ab8[s & 1];
    #pragma unroll
    for (int cc = 0; cc < 2; ++cc){
      const int c = 2 * s + cc;                    // 0..7 -> W8 index
      long wf8[3];
      #pragma unroll
      for (int e = 0; e < 3; ++e)
        wf8[e] = *(const long*)(W8 + ((size_t)((tq + 16 * e) * 8 + c) * 64 + lane) * 8);
      #pragma unroll
      for (int m = 0; m < 8; ++m){
        int row = 16 * m + lo;
        int ad  = row * 64 + (((2 * cc + (hi >> 1)) ^ ((row >> 1) & 3)) << 4) + 8 * (hi & 1);
        long af8 = *(const long*)(ab + ad);
        #pragma unroll
        for (int e = 0; e < 3; ++e)
          acc[e][m] = __builtin_amdgcn_mfma_f32_16x16x32_fp8_fp8(af8, wf8[e], acc[e][m], 0, 0, 0);
      }
    }
    __syncthreads();
  }

  // ---- fold x16 W scale out of the fp8 partial sums ----
  #pragma unroll
  for (int e = 0; e < 3; ++e)
    #pragma unroll
    for (int m = 0; m < 8; ++m)
      #pragma unroll
      for (int r = 0; r < 4; ++r) acc[e][m][r] *= 0.0625f;

  // ---- Phase B: P half, bf16 ----
  for (int s = 0; s < 4; ++s){
    if (s < 3) stage16(s + 1, (s + 1) & 1);
    const char* ab = (const char*)Ab16[s & 1];
    #pragma unroll
    for (int cc = 0; cc < 2; ++cc){
      const int c = 2 * s + cc;                    // 0..7 -> Wp index
      bf16x8 wf[3];
      #pragma unroll
      for (int e = 0; e < 3; ++e)
        wf[e] = *(const bf16x8*)(Wp + ((size_t)((tq + 16 * e) * 8 + c) * 64 + lane) * 8);
      #pragma unroll
      for (int m = 0; m < 8; ++m){
        int row = 16 * m + lo;
        bf16x8 af = *(const bf16x8*)(ab + row * 128 + ((64 * cc + 16 * hi) ^ ((row & 7) << 4)));
        #pragma unroll
        for (int e = 0; e < 3; ++e)
          acc[e][m] = __builtin_amdgcn_mfma_f32_16x16x32_bf16(af, wf[e], acc[e][m], 0, 0, 0);
      }
    }
    __syncthreads();
  }

  // ---- fused gate epilogue (pv from Pbf; absmax-identical per r19/r21) ----
  const int d = 16 * tq + lo;
  const float bb1 = b1[d], bb2 = b2[d], bb3 = b3[d];
  #pragma unroll
  for (int m = 0; m < 8; ++m){
    #pragma unroll
    for (int r = 0; r < 4; ++r){
      const int row = m0 + 16 * m + 4 * hi + r;
      float y1 = acc[0][m][r] + bb1;
      float y2 = acc[1][m][r] + bb2;
      float y3 = acc[2][m][r] + bb3;
      float pv = bf2f(Pbf[(size_t)row * ND + d]);
      float e2 = __expf(2.f * y1);
      float z  = (e2 - 1.f) / (e2 + 1.f);          // tanh
      float rr = 1.f / (1.f + __expf(-y2));        // sigmoid
      float ff = 1.f / (1.f + __expf(-y3));        // sigmoid
      out[(size_t)row * ND + d] = rr * pv + ff * z;
    }
  }
}

extern "C" void kernel_launch(void* const* d_in, const int* in_sizes, int n_in,
                              void* d_out, int out_size, void* d_ws, size_t ws_size,
                              hipStream_t stream){
  const float* P  = (const float*)d_in[0];
  const float* wi = (const float*)d_in[1];
  const float* w1 = (const float*)d_in[2];
  const float* w2 = (const float*)d_in[3];
  const float* w3 = (const float*)d_in[4];
  const float* b1 = (const float*)d_in[5];
  const float* b2 = (const float*)d_in[6];
  const float* b3 = (const float*)d_in[7];
  float* out = (float*)d_out;

  char* ws = (char*)d_ws;
  u8*    PT8   = (u8*)   (ws);                        // 8 MB (fp8 transpose)
  u8*    P8    = (u8*)   (ws + ( 8u << 20));          // 8 MB
  u8*    atn8  = (u8*)   (ws + (16u << 20));          // 8 MB
  u16*   Pbf   = (u16*)  (ws + (24u << 20));          // 16 MB
  u16*   Wp    = (u16*)  (ws + (40u << 20));          // 384 KB bf16 W (c<8)
  u8*    W8    = (u8*)   (ws + (40u << 20) + 524288); // 192 KB fp8 W (c>=8)
  float* sbv   = (float*)(ws + (41u << 20));          // 128 KB

  prep_pt<<<dim3(16, 32), 256, 0, stream>>>(P, wi, Pbf, PT8, P8, sbv);
  prep_w<<<48, 256, 0, stream>>>(w1, w2, w3, Wp, W8);
  attn_kernel<<<512, 256, 0, stream>>>(P, wi, P8, PT8, sbv, atn8);
  mlp_kernel<<<1024, 256, 0, stream>>>(Pbf, atn8, Wp, W8, b1, b2, b3, out);
}

// Round 23
// 106.799 us; speedup vs baseline: 1.0211x; 1.0001x over previous
//
#include <hip/hip_runtime.h>
#include <hip/hip_bf16.h>

typedef unsigned short u16;
typedef unsigned int   u32;
typedef unsigned char  u8;

using bf16x8 = __attribute__((ext_vector_type(8))) short;  // 8 bf16 in 4 VGPRs
using f32x4  = __attribute__((ext_vector_type(4))) float;  // MFMA accumulator

#define NB 32
#define NP 1024
#define ND 256

__device__ __forceinline__ u16 f2bf(float x){
  u32 u = __float_as_uint(x);
  u += 0x7FFFu + ((u >> 16) & 1u);   // round-to-nearest-even
  return (u16)(u >> 16);
}

__device__ __forceinline__ float bf2f(u16 x){
  return __uint_as_float((u32)x << 16);
}

// ---- fp8 e4m3fn pack (builtin word-select must be a LITERAL -> template) ----
__device__ __forceinline__ u8 f2e4m3(float x){
  u32 b = __float_as_uint(x);
  u32 s = (b >> 31) << 7;
  float ax = __uint_as_float(b & 0x7fffffffu);
  if (!(ax < 464.f)) return (u8)(s | 0x7E);            // sat (fn: no inf), NaN->max
  if (ax < 0.001953125f) return (u8)s;                 // < 2^-9 -> 0
  if (ax < 0.015625f){                                 // denormal: m = round(x*512)
    u32 m = (u32)__float2int_rn(ax * 512.f);
    return (u8)(s | m);
  }
  u32 bb = b & 0x7fffffffu;
  bb += 0x7ffffu + ((bb >> 20) & 1u);                  // RNE to 3-bit mantissa
  int e = (int)(bb >> 23) - 127 + 7;
  u32 m = (bb >> 20) & 7u;
  if (e > 15 || (e == 15 && m == 7)) return (u8)(s | 0x7E);
  return (u8)(s | ((u32)e << 3) | m);
}
#if __has_builtin(__builtin_amdgcn_cvt_pk_fp8_f32)
template<bool HI>
__device__ __forceinline__ u32 pk_fp8(float a, float b, u32 old){
  return (u32)__builtin_amdgcn_cvt_pk_fp8_f32(a, b, (int)old, HI);
}
__device__ __forceinline__ u8 f8byte(float x){
  return (u8)(pk_fp8<false>(x, 0.f, 0) & 0xFFu);
}
#else
template<bool HI>
__device__ __forceinline__ u32 pk_fp8(float a, float b, u32 old){
  u32 v = (u32)f2e4m3(a) | ((u32)f2e4m3(b) << 8);
  return HI ? ((old & 0xFFFFu) | (v << 16)) : ((old & 0xFFFF0000u) | v);
}
__device__ __forceinline__ u8 f8byte(float x){ return f2e4m3(x); }
#endif

__device__ __forceinline__ void glds16(const void* g, void* l){
  __builtin_amdgcn_global_load_lds((const __attribute__((address_space(1))) void*)g,
                                   (__attribute__((address_space(3))) void*)l, 16, 0, 0);
}

// ---- fused prep: Pbf (bf16), PT8 (fp8 transpose), P8, sbv ----------------------
__global__ void prep_pt(const float* __restrict__ P, const float* __restrict__ wi,
                        u16* __restrict__ Pbf, u8* __restrict__ PT8,
                        u8* __restrict__ P8, float* __restrict__ sbv){
  const int b = blockIdx.y, jt = blockIdx.x;
  __shared__ __align__(16) u16 T[64][264];       // 33.8 KB (pad 264)
  const int tid = threadIdx.x;
  const int row = tid >> 2;                      // local j 0..63
  const int dq  = tid & 3;                       // d-quarter lane
  const size_t grow = (size_t)b * NP + jt * 64 + row;
  const float* prow = P + grow * ND;
  const float* wbp  = wi + ND;                   // wb = wi[256:512]
  float s = 0.f;
  #pragma unroll
  for (int it = 0; it < 4; ++it){
    const int d0 = it * 64 + dq * 16;            // per-lane 64B-contiguous chunks
    float4 a0 = *(const float4*)(prow + d0);
    float4 a1 = *(const float4*)(prow + d0 + 4);
    float4 a2 = *(const float4*)(prow + d0 + 8);
    float4 a3 = *(const float4*)(prow + d0 + 12);
    float4 w0 = *(const float4*)(wbp + d0);
    float4 w1 = *(const float4*)(wbp + d0 + 4);
    float4 w2 = *(const float4*)(wbp + d0 + 8);
    float4 w3 = *(const float4*)(wbp + d0 + 12);
    s += a0.x*w0.x + a0.y*w0.y + a0.z*w0.z + a0.w*w0.w;
    s += a1.x*w1.x + a1.y*w1.y + a1.z*w1.z + a1.w*w1.w;
    s += a2.x*w2.x + a2.y*w2.y + a2.z*w2.z + a2.w*w2.w;
    s += a3.x*w3.x + a3.y*w3.y + a3.z*w3.z + a3.w*w3.w;
    u16 tmp[16];
    tmp[0]=f2bf(a0.x); tmp[1]=f2bf(a0.y); tmp[2]=f2bf(a0.z); tmp[3]=f2bf(a0.w);
    tmp[4]=f2bf(a1.x); tmp[5]=f2bf(a1.y); tmp[6]=f2bf(a1.z); tmp[7]=f2bf(a1.w);
    tmp[8]=f2bf(a2.x); tmp[9]=f2bf(a2.y); tmp[10]=f2bf(a2.z); tmp[11]=f2bf(a2.w);
    tmp[12]=f2bf(a3.x); tmp[13]=f2bf(a3.y); tmp[14]=f2bf(a3.z); tmp[15]=f2bf(a3.w);
    *(uint4*)&T[row][d0]     = *(uint4*)tmp;
    *(uint4*)&T[row][d0 + 8] = *(uint4*)(tmp + 8);
    *(uint4*)(Pbf + grow * ND + d0)     = *(uint4*)tmp;
    *(uint4*)(Pbf + grow * ND + d0 + 8) = *(uint4*)(tmp + 8);
    // fp8 copy (16 values -> 16 bytes)
    u32 q0 = pk_fp8<false>(a0.x, a0.y, 0); q0 = pk_fp8<true>(a0.z, a0.w, q0);
    u32 q1 = pk_fp8<false>(a1.x, a1.y, 0); q1 = pk_fp8<true>(a1.z, a1.w, q1);
    u32 q2 = pk_fp8<false>(a2.x, a2.y, 0); q2 = pk_fp8<true>(a2.z, a2.w, q2);
    u32 q3 = pk_fp8<false>(a3.x, a3.y, 0); q3 = pk_fp8<true>(a3.z, a3.w, q3);
    uint4 pq; pq.x = q0; pq.y = q1; pq.z = q2; pq.w = q3;
    *(uint4*)(P8 + grow * ND + d0) = pq;
  }
  s += __shfl_xor(s, 1, 64);
  s += __shfl_xor(s, 2, 64);
  if (dq == 0) sbv[grow] = s;
  __syncthreads();
  // fp8 transpose out: PT8[b][d][j]
  #pragma unroll
  for (int it = 0; it < 8; ++it){
    int cc = tid + 256 * it;                     // 256 d-rows x 8 chunks
    int d = cc >> 3, c8 = cc & 7;
    float v0 = bf2f(T[c8 * 8 + 0][d]), v1 = bf2f(T[c8 * 8 + 1][d]);
    float v2 = bf2f(T[c8 * 8 + 2][d]), v3 = bf2f(T[c8 * 8 + 3][d]);
    float v4 = bf2f(T[c8 * 8 + 4][d]), v5 = bf2f(T[c8 * 8 + 5][d]);
    float v6 = bf2f(T[c8 * 8 + 6][d]), v7 = bf2f(T[c8 * 8 + 7][d]);
    u32 lo32 = pk_fp8<false>(v0, v1, 0); lo32 = pk_fp8<true>(v2, v3, lo32);
    u32 hi32 = pk_fp8<false>(v4, v5, 0); hi32 = pk_fp8<true>(v6, v7, hi32);
    uint2 pv; pv.x = lo32; pv.y = hi32;
    *(uint2*)(PT8 + ((size_t)b * ND + d) * NP + jt * 64 + c8 * 8) = pv;
  }
}

// --- prep_w: K-split W pack. c<8 (P half) -> bf16 Wp; c>=8 (attn half) -> fp8 x16
__global__ void prep_w(const float* __restrict__ w1, const float* __restrict__ w2,
                       const float* __restrict__ w3,
                       u16* __restrict__ Wp, u8* __restrict__ W8){
  const int t = blockIdx.x;                       // 0..47
  const float* w = (t < 16) ? w1 : ((t < 32) ? w2 : w3);
  const int tid = threadIdx.x;
  #pragma unroll
  for (int j = 0; j < 4; ++j){
    int item = tid + 256 * j;                     // c*64 + lane (c uniform per wave)
    int c = item >> 6, lane = item & 63;
    int ncol = ((t & 15) << 4) + (lane & 15);
    int k0 = 32 * c + 8 * (lane >> 4);
    if (c < 8){
      u16 tmp[8];
      #pragma unroll
      for (int e = 0; e < 8; ++e) tmp[e] = f2bf(w[(size_t)(k0 + e) * 256 + ncol]);
      *(uint4*)(Wp + ((size_t)(t * 8 + c) * 64 + lane) * 8) = *(uint4*)tmp;
    } else {
      u32 lo32 = pk_fp8<false>(16.f * w[(size_t)(k0+0)*256+ncol], 16.f * w[(size_t)(k0+1)*256+ncol], 0);
      lo32     = pk_fp8<true >(16.f * w[(size_t)(k0+2)*256+ncol], 16.f * w[(size_t)(k0+3)*256+ncol], lo32);
      u32 hi32 = pk_fp8<false>(16.f * w[(size_t)(k0+4)*256+ncol], 16.f * w[(size_t)(k0+5)*256+ncol], 0);
      hi32     = pk_fp8<true >(16.f * w[(size_t)(k0+6)*256+ncol], 16.f * w[(size_t)(k0+7)*256+ncol], hi32);
      uint2 pv; pv.x = lo32; pv.y = hi32;
      *(uint2*)(W8 + ((size_t)(t * 8 + (c - 8)) * 64 + lane) * 8) = pv;
    }
  }
}

// ---------------- attention: full-fp8 operand paths (r22 champion, unchanged) ----
__launch_bounds__(256, 2)
__global__ void attn_kernel(const float* __restrict__ P, const float* __restrict__ wi,
                            const u8* __restrict__ P8, const u8* __restrict__ PT8,
                            const float* __restrict__ sbv, u8* __restrict__ attnb8){
  const int p    = blockIdx.x;
  const int bid  = ((p & 7) << 6) | (p >> 3);     // 64 consecutive bids per XCD
  const int b    = bid >> 4;
  const int q0   = (bid & 15) << 6;
  const int tid  = threadIdx.x;
  const int wave = tid >> 6, lane = tid & 63, lo = lane & 15, hi = lane >> 4;

  __shared__ __align__(16) u8  Kt8[64 * 256];     // 16 KB (fp8)
  __shared__ __align__(16) u8  Vt8[256 * 64];     // 16 KB (fp8)
  __shared__ __align__(16) u8  Sp8[4][16][80];    // 5 KB (fp8 P, pitch 80)
  __shared__ float sls[4][16];                    // per-q rescale factors
  __shared__ float lfin[64];                      // final softmax sums
  __shared__ u32 fastf[4];                        // per-wave fast-path flags
  char* KtB = (char*)Kt8;
  char* VtB = (char*)Vt8;

  // ---- Q fragments (A-operand, fp8): q = 16 * P * wc ----
  long qf8[8];
  {
    const int qrow = q0 + wave * 16 + lo;
    const float* prow = P  + ((size_t)b * NP + qrow) * ND;
    const float* wcp  = wi + 512;
    #pragma unroll
    for (int c = 0; c < 8; ++c){
      const int d0 = 32 * c + 8 * hi;
      float4 a  = *(const float4*)(prow + d0);
      float4 a2 = *(const float4*)(prow + d0 + 4);
      float4 wa  = *(const float4*)(wcp + d0);
      float4 wa2 = *(const float4*)(wcp + d0 + 4);
      u32 w0 = pk_fp8<false>(16.f*a.x*wa.x,  16.f*a.y*wa.y,  0);
      w0     = pk_fp8<true >(16.f*a.z*wa.z,  16.f*a.w*wa.w,  w0);
      u32 w1 = pk_fp8<false>(16.f*a2.x*wa2.x, 16.f*a2.y*wa2.y, 0);
      w1     = pk_fp8<true >(16.f*a2.z*wa2.z, 16.f*a2.w*wa2.w, w1);
      qf8[c] = (long)(((unsigned long long)w1 << 32) | w0);
    }
  }

  f32x4 of[4][4];
  #pragma unroll
  for (int qt = 0; qt < 4; ++qt)
    #pragma unroll
    for (int dt = 0; dt < 4; ++dt) of[qt][dt] = (f32x4){0.f,0.f,0.f,0.f};
  float mx[4] = {-1e30f,-1e30f,-1e30f,-1e30f};
  float ls[4] = {0.f,0.f,0.f,0.f};

  const u8* kslab = P8  + (size_t)b * NP * ND;   // fp8 row-major [j][d]
  const u8* vslab = PT8 + (size_t)b * ND * NP;   // fp8 d-major  [d][j]

  auto stageK = [&](int kt){
    const int kbase = kt * 64;
    #pragma unroll
    for (int it = 0; it < 4; ++it){
      int off = it * 4096 + tid * 16;             // linear LDS dest byte
      int j   = off >> 8;                          // 256B fp8 rows
      int u   = ((off >> 4) & 15) ^ (j & 7);       // source 16B unit
      glds16((const char*)(kslab + (size_t)(kbase + j) * ND + u * 16), KtB + off);
    }
  };
  auto stageV = [&](int kt){
    const int kbase = kt * 64;
    #pragma unroll
    for (int it = 0; it < 4; ++it){
      int off = it * 4096 + tid * 16;
      int d   = off >> 6;                          // 64B fp8 rows
      int t   = (off >> 4) & 3;                    // dest 16B unit
      int u   = t ^ ((d >> 1) & 3);                // source 16B unit (swz even)
      glds16((const char*)(vslab + (size_t)d * NP + kbase + u * 16), VtB + off);
    }
  };

  float sbc[4], sbn[4];
  stageK(0);
  stageV(0);
  #pragma unroll
  for (int nt = 0; nt < 4; ++nt) sbc[nt] = sbv[(size_t)b * NP + nt * 16 + lo];
  __syncthreads();                                 // drain: K0,V0 valid

  for (int kt = 0; kt < 16; ++kt){
    // ---- S = (16Q) K^T / 16 (fp8 MFMA; reads Kt8) ----
    f32x4 s[4];
    #pragma unroll
    for (int nt = 0; nt < 4; ++nt){
      f32x4 acc = (f32x4){0.f,0.f,0.f,0.f};
      #pragma unroll
      for (int c = 0; c < 8; ++c){
        int j  = nt * 16 + lo;
        int ad = j * 256 + (((2 * c + (hi >> 1)) ^ (j & 7)) << 4) + 8 * (hi & 1);
        long kf8 = *(const long*)(KtB + ad);
        acc = __builtin_amdgcn_mfma_f32_16x16x32_fp8_fp8(qf8[c], kf8, acc, 0, 0, 0);
      }
      float sv = sbc[nt];
      #pragma unroll
      for (int r = 0; r < 4; ++r) s[nt][r] = fmaf(acc[r], 0.0625f, sv);
    }

    // ---- deferred online softmax (owning wave: its 16 q rows) ----
    float scale[4] = {1.f, 1.f, 1.f, 1.f};
    int fast = 1;
    {
      float md = -1e30f;
      #pragma unroll
      for (int nt = 0; nt < 4; ++nt)
        #pragma unroll
        for (int r = 0; r < 4; ++r) md = fmaxf(md, s[nt][r] - mx[r]);
      if (!__all(md <= 8.f)){
        fast = 0;
        #pragma unroll
        for (int r = 0; r < 4; ++r){
          float v = fmaxf(fmaxf(s[0][r], s[1][r]), fmaxf(s[2][r], s[3][r]));
          v = fmaxf(v, __shfl_xor(v, 1, 64));
          v = fmaxf(v, __shfl_xor(v, 2, 64));
          v = fmaxf(v, __shfl_xor(v, 4, 64));
          v = fmaxf(v, __shfl_xor(v, 8, 64));
          float mnew = fmaxf(mx[r], v);
          scale[r] = __expf(mx[r] - mnew);
          mx[r] = mnew;
          ls[r] *= scale[r];
        }
      }
    }
    // exp + per-lane partial sums + pack P/8 to Sp8 (p/8 <= 372 < 448 sat)
    #pragma unroll
    for (int nt = 0; nt < 4; ++nt)
      #pragma unroll
      for (int r = 0; r < 4; ++r){
        float pv = __expf(s[nt][r] - mx[r]);
        ls[r] += pv;
        Sp8[wave][4 * hi + r][16 * nt + lo] = f8byte(pv * 0.125f);
      }
    if (lane == 0) fastf[wave] = (u32)fast;
    if (lo == 0){
      #pragma unroll
      for (int r = 0; r < 4; ++r) sls[wave][4 * hi + r] = scale[r];
    }

    __syncthreads();                  // barrier1: Kt reads done; Sp8/sls visible
    if (kt < 15) stageK(kt + 1);      // in flight across rescale+PV; drains at b2

    // ---- cross-wave rescale of O (skipped when all 4 waves were fast) ----
    if (!(fastf[0] & fastf[1] & fastf[2] & fastf[3])){
      #pragma unroll
      for (int qt = 0; qt < 4; ++qt){
        #pragma unroll
        for (int r = 0; r < 4; ++r){
          float sc = sls[qt][4 * hi + r];          // same-addr per 16 lanes: broadcast
          #pragma unroll
          for (int dt = 0; dt < 4; ++dt) of[qt][dt][r] *= sc;
        }
      }
    }

    // ---- O += (P/8) V, fp8 MFMA; this wave owns d in [wave*64, wave*64+64) ----
    #pragma unroll
    for (int kk = 0; kk < 2; ++kk){
      long pa8[4];
      #pragma unroll
      for (int qt = 0; qt < 4; ++qt)
        pa8[qt] = *(const long*)&Sp8[qt][lo][32 * kk + 8 * hi];
      #pragma unroll
      for (int dt = 0; dt < 4; ++dt){
        int d  = wave * 64 + dt * 16 + lo;
        int ad = d * 64 + (((4 * kk + hi) ^ (d & 6)) << 3);
        long vb8 = *(const long*)(VtB + ad);
        #pragma unroll
        for (int qt = 0; qt < 4; ++qt)
          of[qt][dt] = __builtin_amdgcn_mfma_f32_16x16x32_fp8_fp8(pa8[qt], vb8, of[qt][dt], 0, 0, 0);
      }
    }

    __syncthreads();                  // barrier2: Vt+Sp8 reads done; drains K(t+1)
    if (kt < 15){
      stageV(kt + 1);                 // in flight across next QK^T+softmax; drains at b1
      #pragma unroll
      for (int nt = 0; nt < 4; ++nt)
        sbn[nt] = sbv[(size_t)b * NP + (kt + 1) * 64 + nt * 16 + lo];
      sbc[0] = sbn[0]; sbc[1] = sbn[1]; sbc[2] = sbn[2]; sbc[3] = sbn[3];
    }
  }

  // ---- epilogue: publish per-q l, then O = 8*of/l, store fp8 ----
  #pragma unroll
  for (int r = 0; r < 4; ++r){
    ls[r] += __shfl_xor(ls[r], 1, 64);
    ls[r] += __shfl_xor(ls[r], 2, 64);
    ls[r] += __shfl_xor(ls[r], 4, 64);
    ls[r] += __shfl_xor(ls[r], 8, 64);
  }
  if (lo == 0){
    #pragma unroll
    for (int r = 0; r < 4; ++r) lfin[wave * 16 + 4 * hi + r] = ls[r];
  }
  __syncthreads();
  #pragma unroll
  for (int qt = 0; qt < 4; ++qt){
    #pragma unroll
    for (int r = 0; r < 4; ++r){
      const float inv = 8.f / lfin[qt * 16 + 4 * hi + r];   // folds the 1/8 P-scale
      const int qrow = q0 + qt * 16 + 4 * hi + r;
      #pragma unroll
      for (int dt = 0; dt < 4; ++dt){
        float o = of[qt][dt][r] * inv;
        attnb8[((size_t)b * NP + qrow) * ND + wave * 64 + dt * 16 + lo] = f8byte(o);
      }
    }
  }
}

// ---------------- MLP: K-split mixed precision, 32KB LDS -> 4+ blocks/CU ---------
// r22 profile: mlp latency-bound at 20% occupancy; LDS 48KB capped 3 blocks/CU
// while grid 1024 needs 4/CU. Phase B now uses 2 x 8KB BK=32 slices (8 steps,
// dbuf kept, same bytes) -> LDS 32KB -> all 4 blocks resident. Slice layout
// (bijection rule, same pattern as r14's validated V): row pitch 64B, swizzle
// u' = u ^ ((row>>1)&3) -> read quad 4(lo&1)+(hi^((lo>>1)&3)) bijective; glds
// source = within-row 16B permutation (coalesced).
__launch_bounds__(256, 2)
__global__ void mlp_kernel(const u16* __restrict__ Pbf, const u8* __restrict__ attnb8,
                           const u16* __restrict__ Wp, const u8* __restrict__ W8,
                           const float* __restrict__ b1, const float* __restrict__ b2,
                           const float* __restrict__ b3, float* __restrict__ out){
  const int p    = blockIdx.x;
  const int swz  = ((p & 7) << 7) | (p >> 3);     // XCD-chunked
  const int mt   = swz >> 2, cg = swz & 3;
  const int tid  = threadIdx.x;
  const int wave = tid >> 6, lane = tid & 63, lo = lane & 15, hi = lane >> 4;
  const int tq   = 4 * cg + wave;
  const int m0   = mt * 128;

  __shared__ __align__(16) u16 Ab16[2][128 * 32]; // 2 x 8 KB (bf16, BK=32 slices)
  __shared__ __align__(16) u8  Ab8[2][128 * 64];  // 2 x 8 KB (fp8)

  f32x4 acc[3][8];
  #pragma unroll
  for (int e = 0; e < 3; ++e)
    #pragma unroll
    for (int m = 0; m < 8; ++m) acc[e][m] = (f32x4){0.f,0.f,0.f,0.f};

  auto stage16 = [&](int s, int buf){             // Pbf BK=32 slice s (0..7)
    const u16* xs = Pbf + (size_t)m0 * ND + s * 32;
    char* dst = (char*)Ab16[buf];
    #pragma unroll
    for (int it = 0; it < 2; ++it){
      int off = it * 4096 + tid * 16;
      int row = off >> 6;                          // 64B per row
      int u   = ((off >> 4) & 3) ^ ((row >> 1) & 3);
      glds16((const char*)(xs + (size_t)row * ND) + u * 16, dst + off);
    }
  };
  auto stage8 = [&](int s, int buf){              // attnb8 K-slice s (0..3)
    const u8* xs = attnb8 + (size_t)m0 * ND + s * 64;
    char* dst = (char*)Ab8[buf];
    #pragma unroll
    for (int it = 0; it < 2; ++it){
      int off = it * 4096 + tid * 16;
      int row = off >> 6;                          // 64B per row
      int u   = ((off >> 4) & 3) ^ ((row >> 1) & 3);
      glds16((const char*)(xs + (size_t)row * ND + u * 16), dst + off);
    }
  };

  // ---- Phase A: attn half, fp8 ----
  stage8(0, 0);
  __syncthreads();
  for (int s = 0; s < 4; ++s){
    if (s < 3) stage8(s + 1, (s + 1) & 1);
    else       stage16(0, 0);                      // prefetch phase B's first slice
    const char* ab = (const char*)Ab8[s & 1];
    #pragma unroll
    for (int cc = 0; cc < 2; ++cc){
      const int c = 2 * s + cc;                    // 0..7 -> W8 index
      long wf8[3];
      #pragma unroll
      for (int e = 0; e < 3; ++e)
        wf8[e] = *(const long*)(W8 + ((size_t)((tq + 16 * e) * 8 + c) * 64 + lane) * 8);
      #pragma unroll
      for (int m = 0; m < 8; ++m){
        int row = 16 * m + lo;
        int ad  = row * 64 + (((2 * cc + (hi >> 1)) ^ ((row >> 1) & 3)) << 4) + 8 * (hi & 1);
        long af8 = *(const long*)(ab + ad);
        #pragma unroll
        for (int e = 0; e < 3; ++e)
          acc[e][m] = __builtin_amdgcn_mfma_f32_16x16x32_fp8_fp8(af8, wf8[e], acc[e][m], 0, 0, 0);
      }
    }
    __syncthreads();
  }

  // ---- fold x16 W scale out of the fp8 partial sums ----
  #pragma unroll
  for (int e = 0; e < 3; ++e)
    #pragma unroll
    for (int m = 0; m < 8; ++m)
      #pragma unroll
      for (int r = 0; r < 4; ++r) acc[e][m][r] *= 0.0625f;

  // ---- Phase B: P half, bf16, BK=32 slices (8 steps, dbuf) ----
  for (int s = 0; s < 8; ++s){
    if (s < 7) stage16(s + 1, (s + 1) & 1);
    const char* ab = (const char*)Ab16[s & 1];
    bf16x8 wf[3];
    #pragma unroll
    for (int e = 0; e < 3; ++e)
      wf[e] = *(const bf16x8*)(Wp + ((size_t)((tq + 16 * e) * 8 + s) * 64 + lane) * 8);
    #pragma unroll
    for (int m = 0; m < 8; ++m){
      int row = 16 * m + lo;
      int ad  = row * 64 + (((hi) ^ ((row >> 1) & 3)) << 4);
      bf16x8 af = *(const bf16x8*)(ab + ad);
      #pragma unroll
      for (int e = 0; e < 3; ++e)
        acc[e][m] = __builtin_amdgcn_mfma_f32_16x16x32_bf16(af, wf[e], acc[e][m], 0, 0, 0);
    }
    __syncthreads();
  }

  // ---- fused gate epilogue (pv from Pbf) ----
  const int d = 16 * tq + lo;
  const float bb1 = b1[d], bb2 = b2[d], bb3 = b3[d];
  #pragma unroll
  for (int m = 0; m < 8; ++m){
    #pragma unroll
    for (int r = 0; r < 4; ++r){
      const int row = m0 + 16 * m + 4 * hi + r;
      float y1 = acc[0][m][r] + bb1;
      float y2 = acc[1][m][r] + bb2;
      float y3 = acc[2][m][r] + bb3;
      float pv = bf2f(Pbf[(size_t)row * ND + d]);
      float e2 = __expf(2.f * y1);
      float z  = (e2 - 1.f) / (e2 + 1.f);          // tanh
      float rr = 1.f / (1.f + __expf(-y2));        // sigmoid
      float ff = 1.f / (1.f + __expf(-y3));        // sigmoid
      out[(size_t)row * ND + d] = rr * pv + ff * z;
    }
  }
}

extern "C" void kernel_launch(void* const* d_in, const int* in_sizes, int n_in,
                              void* d_out, int out_size, void* d_ws, size_t ws_size,
                              hipStream_t stream){
  const float* P  = (const float*)d_in[0];
  const float* wi = (const float*)d_in[1];
  const float* w1 = (const float*)d_in[2];
  const float* w2 = (const float*)d_in[3];
  const float* w3 = (const float*)d_in[4];
  const float* b1 = (const float*)d_in[5];
  const float* b2 = (const float*)d_in[6];
  const float* b3 = (const float*)d_in[7];
  float* out = (float*)d_out;

  char* ws = (char*)d_ws;
  u8*    PT8   = (u8*)   (ws);                        // 8 MB (fp8 transpose)
  u8*    P8    = (u8*)   (ws + ( 8u << 20));          // 8 MB
  u8*    atn8  = (u8*)   (ws + (16u << 20));          // 8 MB
  u16*   Pbf   = (u16*)  (ws + (24u << 20));          // 16 MB
  u16*   Wp    = (u16*)  (ws + (40u << 20));          // 384 KB bf16 W (c<8)
  u8*    W8    = (u8*)   (ws + (40u << 20) + 524288); // 192 KB fp8 W (c>=8)
  float* sbv   = (float*)(ws + (41u << 20));          // 128 KB

  prep_pt<<<dim3(16, 32), 256, 0, stream>>>(P, wi, Pbf, PT8, P8, sbv);
  prep_w<<<48, 256, 0, stream>>>(w1, w2, w3, Wp, W8);
  attn_kernel<<<512, 256, 0, stream>>>(P, wi, P8, PT8, sbv, atn8);
  mlp_kernel<<<1024, 256, 0, stream>>>(Pbf, atn8, Wp, W8, b1, b2, b3, out);
}

// Round 25
// 106.758 us; speedup vs baseline: 1.0215x; 1.0004x over previous
//
#include <hip/hip_runtime.h>
#include <hip/hip_bf16.h>

typedef unsigned short u16;
typedef unsigned int   u32;
typedef unsigned char  u8;

using bf16x8 = __attribute__((ext_vector_type(8))) short;  // 8 bf16 in 4 VGPRs
using f32x4  = __attribute__((ext_vector_type(4))) float;  // MFMA accumulator

#define NB 32
#define NP 1024
#define ND 256

__device__ __forceinline__ u16 f2bf(float x){
  u32 u = __float_as_uint(x);
  u += 0x7FFFu + ((u >> 16) & 1u);   // round-to-nearest-even
  return (u16)(u >> 16);
}

__device__ __forceinline__ float bf2f(u16 x){
  return __uint_as_float((u32)x << 16);
}

// ---- fp8 e4m3fn pack (builtin word-select must be a LITERAL -> template) ----
__device__ __forceinline__ u8 f2e4m3(float x){
  u32 b = __float_as_uint(x);
  u32 s = (b >> 31) << 7;
  float ax = __uint_as_float(b & 0x7fffffffu);
  if (!(ax < 464.f)) return (u8)(s | 0x7E);            // sat (fn: no inf), NaN->max
  if (ax < 0.001953125f) return (u8)s;                 // < 2^-9 -> 0
  if (ax < 0.015625f){                                 // denormal: m = round(x*512)
    u32 m = (u32)__float2int_rn(ax * 512.f);
    return (u8)(s | m);
  }
  u32 bb = b & 0x7fffffffu;
  bb += 0x7ffffu + ((bb >> 20) & 1u);                  // RNE to 3-bit mantissa
  int e = (int)(bb >> 23) - 127 + 7;
  u32 m = (bb >> 20) & 7u;
  if (e > 15 || (e == 15 && m == 7)) return (u8)(s | 0x7E);
  return (u8)(s | ((u32)e << 3) | m);
}
#if __has_builtin(__builtin_amdgcn_cvt_pk_fp8_f32)
template<bool HI>
__device__ __forceinline__ u32 pk_fp8(float a, float b, u32 old){
  return (u32)__builtin_amdgcn_cvt_pk_fp8_f32(a, b, (int)old, HI);
}
__device__ __forceinline__ u8 f8byte(float x){
  return (u8)(pk_fp8<false>(x, 0.f, 0) & 0xFFu);
}
#else
template<bool HI>
__device__ __forceinline__ u32 pk_fp8(float a, float b, u32 old){
  u32 v = (u32)f2e4m3(a) | ((u32)f2e4m3(b) << 8);
  return HI ? ((old & 0xFFFFu) | (v << 16)) : ((old & 0xFFFF0000u) | v);
}
__device__ __forceinline__ u8 f8byte(float x){ return f2e4m3(x); }
#endif

__device__ __forceinline__ void glds16(const void* g, void* l){
  __builtin_amdgcn_global_load_lds((const __attribute__((address_space(1))) void*)g,
                                   (__attribute__((address_space(3))) void*)l, 16, 0, 0);
}

// ---- fused prep: Pbf (bf16), PT8 (fp8 transpose), P8, sbv ----------------------
__global__ void prep_pt(const float* __restrict__ P, const float* __restrict__ wi,
                        u16* __restrict__ Pbf, u8* __restrict__ PT8,
                        u8* __restrict__ P8, float* __restrict__ sbv){
  const int b = blockIdx.y, jt = blockIdx.x;
  __shared__ __align__(16) u16 T[64][264];       // 33.8 KB (pad 264)
  const int tid = threadIdx.x;
  const int row = tid >> 2;                      // local j 0..63
  const int dq  = tid & 3;                       // d-quarter lane
  const size_t grow = (size_t)b * NP + jt * 64 + row;
  const float* prow = P + grow * ND;
  const float* wbp  = wi + ND;                   // wb = wi[256:512]
  float s = 0.f;
  #pragma unroll
  for (int it = 0; it < 4; ++it){
    const int d0 = it * 64 + dq * 16;            // per-lane 64B-contiguous chunks
    float4 a0 = *(const float4*)(prow + d0);
    float4 a1 = *(const float4*)(prow + d0 + 4);
    float4 a2 = *(const float4*)(prow + d0 + 8);
    float4 a3 = *(const float4*)(prow + d0 + 12);
    float4 w0 = *(const float4*)(wbp + d0);
    float4 w1 = *(const float4*)(wbp + d0 + 4);
    float4 w2 = *(const float4*)(wbp + d0 + 8);
    float4 w3 = *(const float4*)(wbp + d0 + 12);
    s += a0.x*w0.x + a0.y*w0.y + a0.z*w0.z + a0.w*w0.w;
    s += a1.x*w1.x + a1.y*w1.y + a1.z*w1.z + a1.w*w1.w;
    s += a2.x*w2.x + a2.y*w2.y + a2.z*w2.z + a2.w*w2.w;
    s += a3.x*w3.x + a3.y*w3.y + a3.z*w3.z + a3.w*w3.w;
    u16 tmp[16];
    tmp[0]=f2bf(a0.x); tmp[1]=f2bf(a0.y); tmp[2]=f2bf(a0.z); tmp[3]=f2bf(a0.w);
    tmp[4]=f2bf(a1.x); tmp[5]=f2bf(a1.y); tmp[6]=f2bf(a1.z); tmp[7]=f2bf(a1.w);
    tmp[8]=f2bf(a2.x); tmp[9]=f2bf(a2.y); tmp[10]=f2bf(a2.z); tmp[11]=f2bf(a2.w);
    tmp[12]=f2bf(a3.x); tmp[13]=f2bf(a3.y); tmp[14]=f2bf(a3.z); tmp[15]=f2bf(a3.w);
    *(uint4*)&T[row][d0]     = *(uint4*)tmp;
    *(uint4*)&T[row][d0 + 8] = *(uint4*)(tmp + 8);
    *(uint4*)(Pbf + grow * ND + d0)     = *(uint4*)tmp;
    *(uint4*)(Pbf + grow * ND + d0 + 8) = *(uint4*)(tmp + 8);
    // fp8 copy (16 values -> 16 bytes)
    u32 q0 = pk_fp8<false>(a0.x, a0.y, 0); q0 = pk_fp8<true>(a0.z, a0.w, q0);
    u32 q1 = pk_fp8<false>(a1.x, a1.y, 0); q1 = pk_fp8<true>(a1.z, a1.w, q1);
    u32 q2 = pk_fp8<false>(a2.x, a2.y, 0); q2 = pk_fp8<true>(a2.z, a2.w, q2);
    u32 q3 = pk_fp8<false>(a3.x, a3.y, 0); q3 = pk_fp8<true>(a3.z, a3.w, q3);
    uint4 pq; pq.x = q0; pq.y = q1; pq.z = q2; pq.w = q3;
    *(uint4*)(P8 + grow * ND + d0) = pq;
  }
  s += __shfl_xor(s, 1, 64);
  s += __shfl_xor(s, 2, 64);
  if (dq == 0) sbv[grow] = s;
  __syncthreads();
  // fp8 transpose out: PT8[b][d][j]
  #pragma unroll
  for (int it = 0; it < 8; ++it){
    int cc = tid + 256 * it;                     // 256 d-rows x 8 chunks
    int d = cc >> 3, c8 = cc & 7;
    float v0 = bf2f(T[c8 * 8 + 0][d]), v1 = bf2f(T[c8 * 8 + 1][d]);
    float v2 = bf2f(T[c8 * 8 + 2][d]), v3 = bf2f(T[c8 * 8 + 3][d]);
    float v4 = bf2f(T[c8 * 8 + 4][d]), v5 = bf2f(T[c8 * 8 + 5][d]);
    float v6 = bf2f(T[c8 * 8 + 6][d]), v7 = bf2f(T[c8 * 8 + 7][d]);
    u32 lo32 = pk_fp8<false>(v0, v1, 0); lo32 = pk_fp8<true>(v2, v3, lo32);
    u32 hi32 = pk_fp8<false>(v4, v5, 0); hi32 = pk_fp8<true>(v6, v7, hi32);
    uint2 pv; pv.x = lo32; pv.y = hi32;
    *(uint2*)(PT8 + ((size_t)b * ND + d) * NP + jt * 64 + c8 * 8) = pv;
  }
}

// --- prep_w: K-split W pack. c<8 (P half) -> bf16 Wp; c>=8 (attn half) -> fp8 x16
__global__ void prep_w(const float* __restrict__ w1, const float* __restrict__ w2,
                       const float* __restrict__ w3,
                       u16* __restrict__ Wp, u8* __restrict__ W8){
  const int t = blockIdx.x;                       // 0..47
  const float* w = (t < 16) ? w1 : ((t < 32) ? w2 : w3);
  const int tid = threadIdx.x;
  #pragma unroll
  for (int j = 0; j < 4; ++j){
    int item = tid + 256 * j;                     // c*64 + lane (c uniform per wave)
    int c = item >> 6, lane = item & 63;
    int ncol = ((t & 15) << 4) + (lane & 15);
    int k0 = 32 * c + 8 * (lane >> 4);
    if (c < 8){
      u16 tmp[8];
      #pragma unroll
      for (int e = 0; e < 8; ++e) tmp[e] = f2bf(w[(size_t)(k0 + e) * 256 + ncol]);
      *(uint4*)(Wp + ((size_t)(t * 8 + c) * 64 + lane) * 8) = *(uint4*)tmp;
    } else {
      u32 lo32 = pk_fp8<false>(16.f * w[(size_t)(k0+0)*256+ncol], 16.f * w[(size_t)(k0+1)*256+ncol], 0);
      lo32     = pk_fp8<true >(16.f * w[(size_t)(k0+2)*256+ncol], 16.f * w[(size_t)(k0+3)*256+ncol], lo32);
      u32 hi32 = pk_fp8<false>(16.f * w[(size_t)(k0+4)*256+ncol], 16.f * w[(size_t)(k0+5)*256+ncol], 0);
      hi32     = pk_fp8<true >(16.f * w[(size_t)(k0+6)*256+ncol], 16.f * w[(size_t)(k0+7)*256+ncol], hi32);
      uint2 pv; pv.x = lo32; pv.y = hi32;
      *(uint2*)(W8 + ((size_t)(t * 8 + (c - 8)) * 64 + lane) * 8) = pv;
    }
  }
}

// ---------------- attention: full-fp8 operand paths (r22 champion) ---------------
__launch_bounds__(256, 2)
__global__ void attn_kernel(const float* __restrict__ P, const float* __restrict__ wi,
                            const u8* __restrict__ P8, const u8* __restrict__ PT8,
                            const float* __restrict__ sbv, u8* __restrict__ attnb8){
  const int p    = blockIdx.x;
  const int bid  = ((p & 7) << 6) | (p >> 3);     // 64 consecutive bids per XCD
  const int b    = bid >> 4;
  const int q0   = (bid & 15) << 6;
  const int tid  = threadIdx.x;
  const int wave = tid >> 6, lane = tid & 63, lo = lane & 15, hi = lane >> 4;

  __shared__ __align__(16) u8  Kt8[64 * 256];     // 16 KB (fp8)
  __shared__ __align__(16) u8  Vt8[256 * 64];     // 16 KB (fp8)
  __shared__ __align__(16) u8  Sp8[4][16][80];    // 5 KB (fp8 P, pitch 80)
  __shared__ float sls[4][16];                    // per-q rescale factors
  __shared__ float lfin[64];                      // final softmax sums
  __shared__ u32 fastf[4];                        // per-wave fast-path flags
  char* KtB = (char*)Kt8;
  char* VtB = (char*)Vt8;

  // ---- Q fragments (A-operand, fp8): q = 16 * P * wc ----
  long qf8[8];
  {
    const int qrow = q0 + wave * 16 + lo;
    const float* prow = P  + ((size_t)b * NP + qrow) * ND;
    const float* wcp  = wi + 512;
    #pragma unroll
    for (int c = 0; c < 8; ++c){
      const int d0 = 32 * c + 8 * hi;
      float4 a  = *(const float4*)(prow + d0);
      float4 a2 = *(const float4*)(prow + d0 + 4);
      float4 wa  = *(const float4*)(wcp + d0);
      float4 wa2 = *(const float4*)(wcp + d0 + 4);
      u32 w0 = pk_fp8<false>(16.f*a.x*wa.x,  16.f*a.y*wa.y,  0);
      w0     = pk_fp8<true >(16.f*a.z*wa.z,  16.f*a.w*wa.w,  w0);
      u32 w1 = pk_fp8<false>(16.f*a2.x*wa2.x, 16.f*a2.y*wa2.y, 0);
      w1     = pk_fp8<true >(16.f*a2.z*wa2.z, 16.f*a2.w*wa2.w, w1);
      qf8[c] = (long)(((unsigned long long)w1 << 32) | w0);
    }
  }

  f32x4 of[4][4];
  #pragma unroll
  for (int qt = 0; qt < 4; ++qt)
    #pragma unroll
    for (int dt = 0; dt < 4; ++dt) of[qt][dt] = (f32x4){0.f,0.f,0.f,0.f};
  float mx[4] = {-1e30f,-1e30f,-1e30f,-1e30f};
  float ls[4] = {0.f,0.f,0.f,0.f};

  const u8* kslab = P8  + (size_t)b * NP * ND;   // fp8 row-major [j][d]
  const u8* vslab = PT8 + (size_t)b * ND * NP;   // fp8 d-major  [d][j]

  auto stageK = [&](int kt){
    const int kbase = kt * 64;
    #pragma unroll
    for (int it = 0; it < 4; ++it){
      int off = it * 4096 + tid * 16;             // linear LDS dest byte
      int j   = off >> 8;                          // 256B fp8 rows
      int u   = ((off >> 4) & 15) ^ (j & 7);       // source 16B unit
      glds16((const char*)(kslab + (size_t)(kbase + j) * ND + u * 16), KtB + off);
    }
  };
  auto stageV = [&](int kt){
    const int kbase = kt * 64;
    #pragma unroll
    for (int it = 0; it < 4; ++it){
      int off = it * 4096 + tid * 16;
      int d   = off >> 6;                          // 64B fp8 rows
      int t   = (off >> 4) & 3;                    // dest 16B unit
      int u   = t ^ ((d >> 1) & 3);                // source 16B unit (swz even)
      glds16((const char*)(vslab + (size_t)d * NP + kbase + u * 16), VtB + off);
    }
  };

  float sbc[4], sbn[4];
  stageK(0);
  stageV(0);
  #pragma unroll
  for (int nt = 0; nt < 4; ++nt) sbc[nt] = sbv[(size_t)b * NP + nt * 16 + lo];
  __syncthreads();                                 // drain: K0,V0 valid

  for (int kt = 0; kt < 16; ++kt){
    // ---- S = (16Q) K^T / 16 (fp8 MFMA; reads Kt8) ----
    f32x4 s[4];
    #pragma unroll
    for (int nt = 0; nt < 4; ++nt){
      f32x4 acc = (f32x4){0.f,0.f,0.f,0.f};
      #pragma unroll
      for (int c = 0; c < 8; ++c){
        int j  = nt * 16 + lo;
        int ad = j * 256 + (((2 * c + (hi >> 1)) ^ (j & 7)) << 4) + 8 * (hi & 1);
        long kf8 = *(const long*)(KtB + ad);
        acc = __builtin_amdgcn_mfma_f32_16x16x32_fp8_fp8(qf8[c], kf8, acc, 0, 0, 0);
      }
      float sv = sbc[nt];
      #pragma unroll
      for (int r = 0; r < 4; ++r) s[nt][r] = fmaf(acc[r], 0.0625f, sv);
    }

    // ---- deferred online softmax (owning wave: its 16 q rows) ----
    float scale[4] = {1.f, 1.f, 1.f, 1.f};
    int fast = 1;
    {
      float md = -1e30f;
      #pragma unroll
      for (int nt = 0; nt < 4; ++nt)
        #pragma unroll
        for (int r = 0; r < 4; ++r) md = fmaxf(md, s[nt][r] - mx[r]);
      if (!__all(md <= 8.f)){
        fast = 0;
        #pragma unroll
        for (int r = 0; r < 4; ++r){
          float v = fmaxf(fmaxf(s[0][r], s[1][r]), fmaxf(s[2][r], s[3][r]));
          v = fmaxf(v, __shfl_xor(v, 1, 64));
          v = fmaxf(v, __shfl_xor(v, 2, 64));
          v = fmaxf(v, __shfl_xor(v, 4, 64));
          v = fmaxf(v, __shfl_xor(v, 8, 64));
          float mnew = fmaxf(mx[r], v);
          scale[r] = __expf(mx[r] - mnew);
          mx[r] = mnew;
          ls[r] *= scale[r];
        }
      }
    }
    // exp + per-lane partial sums + pack P/8 to Sp8 (p/8 <= 372 < 448 sat)
    #pragma unroll
    for (int nt = 0; nt < 4; ++nt)
      #pragma unroll
      for (int r = 0; r < 4; ++r){
        float pv = __expf(s[nt][r] - mx[r]);
        ls[r] += pv;
        Sp8[wave][4 * hi + r][16 * nt + lo] = f8byte(pv * 0.125f);
      }
    if (lane == 0) fastf[wave] = (u32)fast;
    if (lo == 0){
      #pragma unroll
      for (int r = 0; r < 4; ++r) sls[wave][4 * hi + r] = scale[r];
    }

    __syncthreads();                  // barrier1: Kt reads done; Sp8/sls visible
    if (kt < 15) stageK(kt + 1);      // in flight across rescale+PV; drains at b2

    // ---- cross-wave rescale of O (skipped when all 4 waves were fast) ----
    if (!(fastf[0] & fastf[1] & fastf[2] & fastf[3])){
      #pragma unroll
      for (int qt = 0; qt < 4; ++qt){
        #pragma unroll
        for (int r = 0; r < 4; ++r){
          float sc = sls[qt][4 * hi + r];          // same-addr per 16 lanes: broadcast
          #pragma unroll
          for (int dt = 0; dt < 4; ++dt) of[qt][dt][r] *= sc;
        }
      }
    }

    // ---- O += (P/8) V, fp8 MFMA; this wave owns d in [wave*64, wave*64+64) ----
    #pragma unroll
    for (int kk = 0; kk < 2; ++kk){
      long pa8[4];
      #pragma unroll
      for (int qt = 0; qt < 4; ++qt)
        pa8[qt] = *(const long*)&Sp8[qt][lo][32 * kk + 8 * hi];
      #pragma unroll
      for (int dt = 0; dt < 4; ++dt){
        int d  = wave * 64 + dt * 16 + lo;
        int ad = d * 64 + (((4 * kk + hi) ^ (d & 6)) << 3);
        long vb8 = *(const long*)(VtB + ad);
        #pragma unroll
        for (int qt = 0; qt < 4; ++qt)
          of[qt][dt] = __builtin_amdgcn_mfma_f32_16x16x32_fp8_fp8(pa8[qt], vb8, of[qt][dt], 0, 0, 0);
      }
    }

    __syncthreads();                  // barrier2: Vt+Sp8 reads done; drains K(t+1)
    if (kt < 15){
      stageV(kt + 1);                 // in flight across next QK^T+softmax; drains at b1
      #pragma unroll
      for (int nt = 0; nt < 4; ++nt)
        sbn[nt] = sbv[(size_t)b * NP + (kt + 1) * 64 + nt * 16 + lo];
      sbc[0] = sbn[0]; sbc[1] = sbn[1]; sbc[2] = sbn[2]; sbc[3] = sbn[3];
    }
  }

  // ---- epilogue: publish per-q l, then O = 8*of/l, store fp8 ----
  #pragma unroll
  for (int r = 0; r < 4; ++r){
    ls[r] += __shfl_xor(ls[r], 1, 64);
    ls[r] += __shfl_xor(ls[r], 2, 64);
    ls[r] += __shfl_xor(ls[r], 4, 64);
    ls[r] += __shfl_xor(ls[r], 8, 64);
  }
  if (lo == 0){
    #pragma unroll
    for (int r = 0; r < 4; ++r) lfin[wave * 16 + 4 * hi + r] = ls[r];
  }
  __syncthreads();
  #pragma unroll
  for (int qt = 0; qt < 4; ++qt){
    #pragma unroll
    for (int r = 0; r < 4; ++r){
      const float inv = 8.f / lfin[qt * 16 + 4 * hi + r];   // folds the 1/8 P-scale
      const int qrow = q0 + qt * 16 + 4 * hi + r;
      #pragma unroll
      for (int dt = 0; dt < 4; ++dt){
        float o = of[qt][dt][r] * inv;
        attnb8[((size_t)b * NP + qrow) * ND + wave * 64 + dt * 16 + lo] = f8byte(o);
      }
    }
  }
}

// ---------------- MLP: K-split mixed precision, 32KB LDS (r23 champion) ----------
__launch_bounds__(256, 2)
__global__ void mlp_kernel(const u16* __restrict__ Pbf, const u8* __restrict__ attnb8,
                           const u16* __restrict__ Wp, const u8* __restrict__ W8,
                           const float* __restrict__ b1, const float* __restrict__ b2,
                           const float* __restrict__ b3, float* __restrict__ out){
  const int p    = blockIdx.x;
  const int swz  = ((p & 7) << 7) | (p >> 3);     // XCD-chunked
  const int mt   = swz >> 2, cg = swz & 3;
  const int tid  = threadIdx.x;
  const int wave = tid >> 6, lane = tid & 63, lo = lane & 15, hi = lane >> 4;
  const int tq   = 4 * cg + wave;
  const int m0   = mt * 128;

  __shared__ __align__(16) u16 Ab16[2][128 * 32]; // 2 x 8 KB (bf16, BK=32 slices)
  __shared__ __align__(16) u8  Ab8[2][128 * 64];  // 2 x 8 KB (fp8)

  f32x4 acc[3][8];
  #pragma unroll
  for (int e = 0; e < 3; ++e)
    #pragma unroll
    for (int m = 0; m < 8; ++m) acc[e][m] = (f32x4){0.f,0.f,0.f,0.f};

  auto stage16 = [&](int s, int buf){             // Pbf BK=32 slice s (0..7)
    const u16* xs = Pbf + (size_t)m0 * ND + s * 32;
    char* dst = (char*)Ab16[buf];
    #pragma unroll
    for (int it = 0; it < 2; ++it){
      int off = it * 4096 + tid * 16;
      int row = off >> 6;                          // 64B per row
      int u   = ((off >> 4) & 3) ^ ((row >> 1) & 3);
      glds16((const char*)(xs + (size_t)row * ND) + u * 16, dst + off);
    }
  };
  auto stage8 = [&](int s, int buf){              // attnb8 K-slice s (0..3)
    const u8* xs = attnb8 + (size_t)m0 * ND + s * 64;
    char* dst = (char*)Ab8[buf];
    #pragma unroll
    for (int it = 0; it < 2; ++it){
      int off = it * 4096 + tid * 16;
      int row = off >> 6;                          // 64B per row
      int u   = ((off >> 4) & 3) ^ ((row >> 1) & 3);
      glds16((const char*)(xs + (size_t)row * ND + u * 16), dst + off);
    }
  };

  // ---- Phase A: attn half, fp8 ----
  stage8(0, 0);
  __syncthreads();
  for (int s = 0; s < 4; ++s){
    if (s < 3) stage8(s + 1, (s + 1) & 1);
    else       stage16(0, 0);                      // prefetch phase B's first slice
    const char* ab = (const char*)Ab8[s & 1];
    #pragma unroll
    for (int cc = 0; cc < 2; ++cc){
      const int c = 2 * s + cc;                    // 0..7 -> W8 index
      long wf8[3];
      #pragma unroll
      for (int e = 0; e < 3; ++e)
        wf8[e] = *(const long*)(W8 + ((size_t)((tq + 16 * e) * 8 + c) * 64 + lane) * 8);
      #pragma unroll
      for (int m = 0; m < 8; ++m){
        int row = 16 * m + lo;
        int ad  = row * 64 + (((2 * cc + (hi >> 1)) ^ ((row >> 1) & 3)) << 4) + 8 * (hi & 1);
        long af8 = *(const long*)(ab + ad);
        #pragma unroll
        for (int e = 0; e < 3; ++e)
          acc[e][m] = __builtin_amdgcn_mfma_f32_16x16x32_fp8_fp8(af8, wf8[e], acc[e][m], 0, 0, 0);
      }
    }
    __syncthreads();
  }

  // ---- fold x16 W scale out of the fp8 partial sums ----
  #pragma unroll
  for (int e = 0; e < 3; ++e)
    #pragma unroll
    for (int m = 0; m < 8; ++m)
      #pragma unroll
      for (int r = 0; r < 4; ++r) acc[e][m][r] *= 0.0625f;

  // ---- Phase B: P half, bf16, BK=32 slices (8 steps, dbuf) ----
  for (int s = 0; s < 8; ++s){
    if (s < 7) stage16(s + 1, (s + 1) & 1);
    const char* ab = (const char*)Ab16[s & 1];
    bf16x8 wf[3];
    #pragma unroll
    for (int e = 0; e < 3; ++e)
      wf[e] = *(const bf16x8*)(Wp + ((size_t)((tq + 16 * e) * 8 + s) * 64 + lane) * 8);
    #pragma unroll
    for (int m = 0; m < 8; ++m){
      int row = 16 * m + lo;
      int ad  = row * 64 + (((hi) ^ ((row >> 1) & 3)) << 4);
      bf16x8 af = *(const bf16x8*)(ab + ad);
      #pragma unroll
      for (int e = 0; e < 3; ++e)
        acc[e][m] = __builtin_amdgcn_mfma_f32_16x16x32_bf16(af, wf[e], acc[e][m], 0, 0, 0);
    }
    __syncthreads();
  }

  // ---- fused gate epilogue (pv from Pbf) ----
  const int d = 16 * tq + lo;
  const float bb1 = b1[d], bb2 = b2[d], bb3 = b3[d];
  #pragma unroll
  for (int m = 0; m < 8; ++m){
    #pragma unroll
    for (int r = 0; r < 4; ++r){
      const int row = m0 + 16 * m + 4 * hi + r;
      float y1 = acc[0][m][r] + bb1;
      float y2 = acc[1][m][r] + bb2;
      float y3 = acc[2][m][r] + bb3;
      float pv = bf2f(Pbf[(size_t)row * ND + d]);
      float e2 = __expf(2.f * y1);
      float z  = (e2 - 1.f) / (e2 + 1.f);          // tanh
      float rr = 1.f / (1.f + __expf(-y2));        // sigmoid
      float ff = 1.f / (1.f + __expf(-y3));        // sigmoid
      out[(size_t)row * ND + d] = rr * pv + ff * z;
    }
  }
}

extern "C" void kernel_launch(void* const* d_in, const int* in_sizes, int n_in,
                              void* d_out, int out_size, void* d_ws, size_t ws_size,
                              hipStream_t stream){
  const float* P  = (const float*)d_in[0];
  const float* wi = (const float*)d_in[1];
  const float* w1 = (const float*)d_in[2];
  const float* w2 = (const float*)d_in[3];
  const float* w3 = (const float*)d_in[4];
  const float* b1 = (const float*)d_in[5];
  const float* b2 = (const float*)d_in[6];
  const float* b3 = (const float*)d_in[7];
  float* out = (float*)d_out;

  char* ws = (char*)d_ws;
  u8*    PT8   = (u8*)   (ws);                        // 8 MB (fp8 transpose)
  u8*    P8    = (u8*)   (ws + ( 8u << 20));          // 8 MB
  u8*    atn8  = (u8*)   (ws + (16u << 20));          // 8 MB
  u16*   Pbf   = (u16*)  (ws + (24u << 20));          // 16 MB
  u16*   Wp    = (u16*)  (ws + (40u << 20));          // 384 KB bf16 W (c<8)
  u8*    W8    = (u8*)   (ws + (40u << 20) + 524288); // 192 KB fp8 W (c>=8)
  float* sbv   = (float*)(ws + (41u << 20));          // 128 KB

  prep_pt<<<dim3(16, 32), 256, 0, stream>>>(P, wi, Pbf, PT8, P8, sbv);
  prep_w<<<48, 256, 0, stream>>>(w1, w2, w3, Wp, W8);
  attn_kernel<<<512, 256, 0, stream>>>(P, wi, P8, PT8, sbv, atn8);
  mlp_kernel<<<1024, 256, 0, stream>>>(Pbf, atn8, Wp, W8, b1, b2, b3, out);
}